// Round 12
// baseline (3833.260 us; speedup 1.0000x reference)
//
#include <hip/hip_runtime.h>

// GNN: 2-layer bipartite GraphConv + link decoder.
// Round 12: host-side aggregation -> src-swept bucket kernel with fp32 LDS
// accumulators (edges sorted by src, one block per 128-dst bucket; all blocks
// sweep the src range in sync -> L2-resident window, L3 traffic ~compulsory).
// Virus-side agg stays per-dst-wave. Conv/decoder/W1-fold as R10.

#define D 128
#define PGB 256   // partition blocks per side

typedef float f32x4 __attribute__((ext_vector_type(4)));
typedef short s16x8 __attribute__((ext_vector_type(8)));

__device__ __forceinline__ float lo16(unsigned u) { return __uint_as_float(u << 16); }
__device__ __forceinline__ float hi16(unsigned u) { return __uint_as_float(u & 0xffff0000u); }
__device__ __forceinline__ unsigned short pkb(float f) {
  unsigned b = __float_as_uint(f);
  return (unsigned short)((b + 0x7fffu + ((b >> 16) & 1u)) >> 16);
}
__device__ __forceinline__ unsigned pk2(float a, float b) {
  return (unsigned)pkb(a) | ((unsigned)pkb(b) << 16);
}

union U4S8 { uint4 u; s16x8 s; };

// ---------------- sort A (merged): vh edges by SRC bucket, hv edges by DST
// bucket — both key on virus-id>>9 (nbins 196 each). side0 payload packs full
// (dst<<17)|src (15+17 bits); side1 packs ((dst&511)<<17)|src as before.

__global__ __launch_bounds__(256) void part_hist2_k(
    const int* __restrict__ key0, const int* __restrict__ key1,
    int* __restrict__ histmat, int E, int nbins0, int nbins1, int shift) {
  __shared__ int hist[256];
  const int t = threadIdx.x;
  const int side = blockIdx.x >> 8, blk = blockIdx.x & 255;
  const int* __restrict__ key = side ? key1 : key0;
  const int binbase = side ? nbins0 : 0;
  const int nbins = side ? nbins1 : nbins0;
  hist[t] = 0;
  __syncthreads();
  const int chunk = (E + PGB - 1) / PGB;
  const int e0 = blk * chunk, e1 = min(E, e0 + chunk);
  for (int i = e0 + t; i < e1; i += 256)
    atomicAdd(&hist[key[i] >> shift], 1);
  __syncthreads();
  if (t < nbins)
    histmat[(size_t)(binbase + t) * PGB + blk] = hist[t];
}

__global__ void scan_chunk_k(const int* __restrict__ in, int* __restrict__ out,
                             int* __restrict__ sums, int n) {
  __shared__ int lds[256];
  int t = threadIdx.x;
  int base = blockIdx.x * 1024 + t * 4;
  int v0 = (base + 0 < n) ? in[base + 0] : 0;
  int v1 = (base + 1 < n) ? in[base + 1] : 0;
  int v2 = (base + 2 < n) ? in[base + 2] : 0;
  int v3 = (base + 3 < n) ? in[base + 3] : 0;
  int s = v0 + v1 + v2 + v3;
  lds[t] = s;
  __syncthreads();
  for (int off = 1; off < 256; off <<= 1) {
    int x = (t >= off) ? lds[t - off] : 0;
    __syncthreads();
    lds[t] += x;
    __syncthreads();
  }
  int excl = lds[t] - s;
  if (t == 255) sums[blockIdx.x] = lds[255];
  if (base + 0 < n) out[base + 0] = excl; excl += v0;
  if (base + 1 < n) out[base + 1] = excl; excl += v1;
  if (base + 2 < n) out[base + 2] = excl; excl += v2;
  if (base + 3 < n) out[base + 3] = excl;
}

__global__ void scan_tops_k(int* __restrict__ sums, int nb) {
  if (threadIdx.x == 0 && blockIdx.x == 0) {
    int run = 0;
    for (int i = 0; i < nb; ++i) { int x = sums[i]; sums[i] = run; run += x; }
  }
}

__global__ void scan_add_k(int* __restrict__ out, const int* __restrict__ sums, int n) {
  int i = blockIdx.x * 256 + threadIdx.x;
  if (i < n) out[i] += sums[i >> 10];
}

__global__ __launch_bounds__(256) void part_scatter2_k(
    const int* __restrict__ src0, const int* __restrict__ dst0,
    const int* __restrict__ src1, const int* __restrict__ dst1,
    const int* __restrict__ histoff, unsigned* __restrict__ out,
    int E, int nbins0, int nbins1, int shift) {
  __shared__ int cur[256];
  const int t = threadIdx.x;
  const int side = blockIdx.x >> 8, blk = blockIdx.x & 255;
  const int binbase = side ? nbins0 : 0;
  const int nbins = side ? nbins1 : nbins0;
  if (t < nbins) cur[t] = histoff[(size_t)(binbase + t) * PGB + blk];
  __syncthreads();
  const int chunk = (E + PGB - 1) / PGB;
  const int e0 = blk * chunk, e1 = min(E, e0 + chunk);
  const int mask = (1 << shift) - 1;
  for (int i = e0 + t; i < e1; i += 256) {
    int b; unsigned pk;
    if (side) {
      int d = dst1[i], s = src1[i];
      b = d >> shift;
      pk = ((unsigned)(d & mask) << 17) | (unsigned)s;
    } else {
      int d = dst0[i], s = src0[i];
      b = s >> shift;                       // key = SRC bucket
      pk = ((unsigned)d << 17) | (unsigned)s;  // full dst(15b) | src(17b)
    }
    int p = atomicAdd(&cur[b], 1);   // LDS atomic
    out[p] = pk;
  }
}

// ---------------- sort B: src-sorted P0 stream partitioned by dst bucket ----
// P0 entry u = (dst<<17)|src; dst bucket = u>>24 (dst>>7). Pool keeps
// (dl<<17)|src with dl = dst&127 (u & 0xFFFFFF).

__global__ __launch_bounds__(256) void histB_k(
    const unsigned* __restrict__ P, int* __restrict__ histmat, int E, int nbins) {
  __shared__ int hist[256];
  const int t = threadIdx.x, blk = blockIdx.x;
  hist[t] = 0;
  __syncthreads();
  const int chunk = (E + PGB - 1) / PGB;
  const int e0 = blk * chunk, e1 = min(E, e0 + chunk);
  for (int i = e0 + t; i < e1; i += 256)
    atomicAdd(&hist[P[i] >> 24], 1);
  __syncthreads();
  if (t < nbins) histmat[(size_t)t * PGB + blk] = hist[t];
}

__global__ __launch_bounds__(256) void scatB_k(
    const unsigned* __restrict__ P, const int* __restrict__ histoff,
    unsigned* __restrict__ pool, int E, int nbins) {
  __shared__ int cur[256];
  const int t = threadIdx.x, blk = blockIdx.x;
  if (t < nbins) cur[t] = histoff[(size_t)t * PGB + blk];
  __syncthreads();
  const int chunk = (E + PGB - 1) / PGB;
  const int e0 = blk * chunk, e1 = min(E, e0 + chunk);
  for (int i = e0 + t; i < e1; i += 256) {
    unsigned u = P[i];
    int p = atomicAdd(&cur[u >> 24], 1);   // LDS atomic
    pool[p] = u & 0xFFFFFFu;
  }
}

// ---------------- CSR finalize for virus dsts (side1 of sort A) ----------------

__global__ __launch_bounds__(256) void csr_binV_k(
    const unsigned* __restrict__ binned, const int* __restrict__ histoff,
    int* __restrict__ csr, int* __restrict__ off, int* __restrict__ cnt,
    float* __restrict__ inv, int E, int nbins0, int nbinsTot, int N) {
  __shared__ int lcnt[512], lex[512], tmp[256];
  const int t = threadIdx.x;
  const int bin = blockIdx.x + nbins0;   // global bin (side1 range)
  const int lb = blockIdx.x;
  const int e0 = histoff[(size_t)bin * PGB];
  const int e1 = (bin + 1 < nbinsTot) ? histoff[(size_t)(bin + 1) * PGB] : 2 * E;
  lcnt[t] = 0; lcnt[t + 256] = 0;
  __syncthreads();
  for (int i = e0 + t; i < e1; i += 256)
    atomicAdd(&lcnt[binned[i] >> 17], 1);   // LDS atomic
  __syncthreads();
  int a = lcnt[t], b = lcnt[t + 256];
  tmp[t] = a; __syncthreads();
  for (int o = 1; o < 256; o <<= 1) {
    int x = (t >= o) ? tmp[t - o] : 0;
    __syncthreads(); tmp[t] += x; __syncthreads();
  }
  int inclA = tmp[t], totA = tmp[255];
  __syncthreads();
  tmp[t] = b; __syncthreads();
  for (int o = 1; o < 256; o <<= 1) {
    int x = (t >= o) ? tmp[t - o] : 0;
    __syncthreads(); tmp[t] += x; __syncthreads();
  }
  int inclB = tmp[t];
  lex[t] = inclA - a;
  lex[t + 256] = totA + inclB - b;
  __syncthreads();
  const int based = lb << 9;
  const int nd = min(512, N - based);
  for (int dl = t; dl < nd; dl += 256) {
    int c = lcnt[dl];
    off[based + dl] = e0 - E + lex[dl];
    cnt[based + dl] = c;
    inv[based + dl] = 1.0f / fmaxf((float)c, 1.0f);
  }
  __syncthreads();
  lcnt[t] = lex[t]; lcnt[t + 256] = lex[t + 256];
  __syncthreads();
  for (int i = e0 + t; i < e1; i += 256) {
    unsigned u = binned[i];
    int dl = (int)(u >> 17);
    int p = atomicAdd(&lcnt[dl], 1);   // LDS atomic
    csr[e0 - E + p] = (int)(u & 0x1FFFFu);
  }
}

// ---------------- conversions / weight prep ----------------

__global__ void cvt_bf16_k(const float* __restrict__ in, unsigned short* __restrict__ out, int n4) {
  int i = blockIdx.x * 256 + threadIdx.x;
  if (i < n4) {
    float4 v = ((const float4*)in)[i];
    ushort4 o;
    o.x = pkb(v.x); o.y = pkb(v.y); o.z = pkb(v.z); o.w = pkb(v.w);
    ((ushort4*)out)[i] = o;
  }
}

__global__ void pack_wcat_k(const float* __restrict__ Wrel, const float* __restrict__ Wroot,
                            unsigned short* __restrict__ Wcat) {
  int idx = blockIdx.x * 256 + threadIdx.x;  // 32768
  int n = idx >> 8, k = idx & 255;
  float v = (k < 128) ? Wrel[(n << 7) + k] : Wroot[(n << 7) + k - 128];
  Wcat[idx] = pkb(v);
}

__global__ __launch_bounds__(256) void fuse_w_k(
    const float* __restrict__ W1, const float* __restrict__ Wrel,
    const float* __restrict__ Wroot, const float* __restrict__ brel,
    const float* __restrict__ b1, unsigned short* __restrict__ Wf,
    float* __restrict__ biasF) {
  const int i = blockIdx.x;
  const int kk = threadIdx.x;
  const float* __restrict__ Wsrc = (kk < 128) ? Wrel : Wroot;
  const int k = kk & 127;
  float s = 0.f;
  for (int o = 0; o < 128; ++o)
    s += W1[i * 128 + o] * Wsrc[o * 128 + k];
  Wf[i * 256 + kk] = pkb(s);
  if (kk == 0) {
    float sb = b1 ? b1[i] : 0.f;
    for (int o = 0; o < 128; ++o) sb += W1[i * 128 + o] * brel[o];
    biasF[i] = sb;
  }
}

// ---------------- host-side bucket aggregation (src-swept, LDS fp32 accum) ----
// One block per 128-dst bucket. Pool is src-ascending -> all blocks sweep the
// src feature array in sync (L2-resident window). Stride 129 pad: LDS bank of
// accs[dl*129+e] = (dl+e)%32 -> random dl spreads 64 lanes across banks.

__global__ __launch_bounds__(256) void bucket_agg_k(
    const unsigned short* __restrict__ xsrc, const unsigned* __restrict__ pool,
    const int* __restrict__ histoffB, unsigned short* __restrict__ mean,
    int nbins, int E, int N) {
  __shared__ float accs[128 * 129];
  __shared__ int cnts[128];
  const int t = threadIdx.x;
  const int bin = blockIdx.x;
  const int e0 = histoffB[(size_t)bin * PGB];
  const int e1 = (bin + 1 < nbins) ? histoffB[(size_t)(bin + 1) * PGB] : E;
  for (int i = t; i < 128 * 129; i += 256) accs[i] = 0.f;
  if (t < 128) cnts[t] = 0;
  __syncthreads();

  for (int i = e0 + t; i < e1; i += 256) {
    unsigned u = pool[i];
    const int dl = (int)(u >> 17);
    const unsigned short* __restrict__ r = xsrc + (size_t)(u & 0x1FFFFu) * 128;
    float* __restrict__ a = accs + dl * 129;
    atomicAdd(&cnts[dl], 1);
#pragma unroll
    for (int b = 0; b < 4; ++b) {
      uint4 v0 = *(const uint4*)(r + b * 32);
      uint4 v1 = *(const uint4*)(r + b * 32 + 8);
      uint4 v2 = *(const uint4*)(r + b * 32 + 16);
      uint4 v3 = *(const uint4*)(r + b * 32 + 24);
      float* __restrict__ ab = a + b * 32;
      atomicAdd(&ab[0],  lo16(v0.x)); atomicAdd(&ab[1],  hi16(v0.x));
      atomicAdd(&ab[2],  lo16(v0.y)); atomicAdd(&ab[3],  hi16(v0.y));
      atomicAdd(&ab[4],  lo16(v0.z)); atomicAdd(&ab[5],  hi16(v0.z));
      atomicAdd(&ab[6],  lo16(v0.w)); atomicAdd(&ab[7],  hi16(v0.w));
      atomicAdd(&ab[8],  lo16(v1.x)); atomicAdd(&ab[9],  hi16(v1.x));
      atomicAdd(&ab[10], lo16(v1.y)); atomicAdd(&ab[11], hi16(v1.y));
      atomicAdd(&ab[12], lo16(v1.z)); atomicAdd(&ab[13], hi16(v1.z));
      atomicAdd(&ab[14], lo16(v1.w)); atomicAdd(&ab[15], hi16(v1.w));
      atomicAdd(&ab[16], lo16(v2.x)); atomicAdd(&ab[17], hi16(v2.x));
      atomicAdd(&ab[18], lo16(v2.y)); atomicAdd(&ab[19], hi16(v2.y));
      atomicAdd(&ab[20], lo16(v2.z)); atomicAdd(&ab[21], hi16(v2.z));
      atomicAdd(&ab[22], lo16(v2.w)); atomicAdd(&ab[23], hi16(v2.w));
      atomicAdd(&ab[24], lo16(v3.x)); atomicAdd(&ab[25], hi16(v3.x));
      atomicAdd(&ab[26], lo16(v3.y)); atomicAdd(&ab[27], hi16(v3.y));
      atomicAdd(&ab[28], lo16(v3.z)); atomicAdd(&ab[29], hi16(v3.z));
      atomicAdd(&ab[30], lo16(v3.w)); atomicAdd(&ab[31], hi16(v3.w));
    }
  }
  __syncthreads();

  const int based = bin << 7;
  for (int idx = t; idx < 128 * 128; idx += 256) {
    int dl = idx >> 7, e = idx & 127;
    int row = based + dl;
    if (row < N) {
      float iv = 1.0f / fmaxf((float)cnts[dl], 1.f);
      mean[(size_t)row * 128 + e] = pkb(accs[dl * 129 + e] * iv);
    }
  }
}

// ---------------- virus-side aggregation: one wave/dst, 16 in flight ----------------

__global__ __launch_bounds__(256) void agg1_k(
    const unsigned short* __restrict__ xsrc, const int* __restrict__ csr,
    const int* __restrict__ off, const int* __restrict__ cnt,
    const float* __restrict__ inv, unsigned short* __restrict__ mean, int ndst) {
  int wid = blockIdx.x * 4 + (threadIdx.x >> 6);
  int lane = threadIdx.x & 63;
  if (wid >= ndst) return;
  int o = off[wid], deg = cnt[wid];
  int q = lane >> 4, sl = lane & 15;
  float acc[8] = {0.f, 0.f, 0.f, 0.f, 0.f, 0.f, 0.f, 0.f};
  int sN[4];
#pragma unroll
  for (int j = 0; j < 4; ++j) {
    int e = j * 4 + q;
    sN[j] = (e < deg) ? csr[o + e] : -1;
  }
  for (int i = 0; i < deg; i += 16) {
    int cu[4];
#pragma unroll
    for (int j = 0; j < 4; ++j) {
      cu[j] = sN[j];
      int e = i + 16 + j * 4 + q;
      sN[j] = (e < deg) ? csr[o + e] : -1;
    }
    uint4 v[4];
#pragma unroll
    for (int j = 0; j < 4; ++j)
      if (cu[j] >= 0) v[j] = *(const uint4*)(xsrc + (size_t)cu[j] * 128 + sl * 8);
#pragma unroll
    for (int j = 0; j < 4; ++j) {
      if (cu[j] >= 0) {
        acc[0] += lo16(v[j].x); acc[1] += hi16(v[j].x);
        acc[2] += lo16(v[j].y); acc[3] += hi16(v[j].y);
        acc[4] += lo16(v[j].z); acc[5] += hi16(v[j].z);
        acc[6] += lo16(v[j].w); acc[7] += hi16(v[j].w);
      }
    }
  }
#pragma unroll
  for (int j = 0; j < 8; ++j) {
    acc[j] += __shfl_xor(acc[j], 16);
    acc[j] += __shfl_xor(acc[j], 32);
  }
  if (q == 0) {
    float iv = inv[wid];
    uint4 r;
    r.x = pk2(acc[0] * iv, acc[1] * iv);
    r.y = pk2(acc[2] * iv, acc[3] * iv);
    r.z = pk2(acc[4] * iv, acc[5] * iv);
    r.w = pk2(acc[6] * iv, acc[7] * iv);
    *(uint4*)(mean + (size_t)wid * 128 + sl * 8) = r;
  }
}

// ---------------- merged conv GEMM (both sides), 64 rows/block ----------------

__global__ __launch_bounds__(256) void conv2_k(
    const unsigned short* __restrict__ A1a, const unsigned short* __restrict__ A2a,
    const unsigned short* __restrict__ Wa, const float* __restrict__ ba,
    unsigned short* __restrict__ outa, int na,
    const unsigned short* __restrict__ A1b, const unsigned short* __restrict__ A2b,
    const unsigned short* __restrict__ Wb, const float* __restrict__ bb_,
    unsigned short* __restrict__ outb, int nb, int nblk0, int relu) {
  int blk = blockIdx.x;
  const unsigned short *A1, *A2, *W;
  const float* bias; unsigned short* out; int n;
  if (blk < nblk0) { A1 = A1a; A2 = A2a; W = Wa; bias = ba; out = outa; n = na; }
  else { blk -= nblk0; A1 = A1b; A2 = A2b; W = Wb; bias = bb_; out = outb; n = nb; }

  const int t = threadIdx.x;
  const int l = t & 63, wv = t >> 6;
  const int g = l >> 4;
  const int row0 = blk * 64 + wv * 16;
  int r = row0 + (l & 15); r = r < n ? r : n - 1;

  s16x8 av[8];
#pragma unroll
  for (int c = 0; c < 4; ++c)
    av[c] = *(const s16x8*)(A1 + (size_t)r * 128 + c * 32 + g * 8);
#pragma unroll
  for (int c = 0; c < 4; ++c)
    av[4 + c] = *(const s16x8*)(A2 + (size_t)r * 128 + c * 32 + g * 8);

  f32x4 acc[8] = {};
#pragma unroll
  for (int ch = 0; ch < 8; ++ch) {
#pragma unroll
    for (int fc = 0; fc < 8; ++fc) {
      s16x8 bv = *(const s16x8*)(W + (size_t)(fc * 16 + (l & 15)) * 256 + ch * 32 + g * 8);
      acc[fc] = __builtin_amdgcn_mfma_f32_16x16x32_bf16(av[ch], bv, acc[fc], 0, 0, 0);
    }
  }

#pragma unroll
  for (int fc = 0; fc < 8; ++fc) {
    int col = fc * 16 + (l & 15);
    float bv = bias[col];
    int rbase = row0 + g * 4;
#pragma unroll
    for (int reg = 0; reg < 4; ++reg) {
      int row = rbase + reg;
      if (row < n) {
        float v = acc[fc][reg] + bv;
        if (relu) v = fmaxf(v, 0.f);
        out[(size_t)row * 128 + col] = pkb(v);
      }
    }
  }
}

// ---------------- decoder: h1 = relu(Pv[lv]-Ph[lh]); stage2 MFMA; dot ----------

__global__ __launch_bounds__(256) void dec2_k(
    const unsigned short* __restrict__ Pv, const unsigned short* __restrict__ Ph,
    const int* __restrict__ lv, const int* __restrict__ lh,
    const unsigned short* __restrict__ W2b, const float* __restrict__ b2,
    const float* __restrict__ Wp, const float* __restrict__ bp,
    float* __restrict__ out, int L) {
  const int t = threadIdx.x;
  const int l = t & 63, wv = t >> 6;
  const int g = l >> 4;
  const int row0 = blockIdx.x * 64 + wv * 16;

  int rowc = row0 + (l & 15);
  rowc = rowc < L ? rowc : L - 1;
  const int iv = lv[rowc], ih = lh[rowc];
  const unsigned short* __restrict__ pv = Pv + (size_t)iv * 128 + g * 8;
  const unsigned short* __restrict__ ph = Ph + (size_t)ih * 128 + g * 8;

  uint4 A[4], B[4];
#pragma unroll
  for (int ch = 0; ch < 4; ++ch) A[ch] = *(const uint4*)(pv + ch * 32);
#pragma unroll
  for (int ch = 0; ch < 4; ++ch) B[ch] = *(const uint4*)(ph + ch * 32);

  s16x8 e[4];
#pragma unroll
  for (int ch = 0; ch < 4; ++ch) {
    U4S8 u;
    u.u.x = pk2(fmaxf(lo16(A[ch].x) - lo16(B[ch].x), 0.f), fmaxf(hi16(A[ch].x) - hi16(B[ch].x), 0.f));
    u.u.y = pk2(fmaxf(lo16(A[ch].y) - lo16(B[ch].y), 0.f), fmaxf(hi16(A[ch].y) - hi16(B[ch].y), 0.f));
    u.u.z = pk2(fmaxf(lo16(A[ch].z) - lo16(B[ch].z), 0.f), fmaxf(hi16(A[ch].z) - hi16(B[ch].z), 0.f));
    u.u.w = pk2(fmaxf(lo16(A[ch].w) - lo16(B[ch].w), 0.f), fmaxf(hi16(A[ch].w) - hi16(B[ch].w), 0.f));
    e[ch] = u.s;
  }

  f32x4 acc2[2] = {};
#pragma unroll
  for (int kc = 0; kc < 4; ++kc) {
#pragma unroll
    for (int fc = 0; fc < 2; ++fc) {
      s16x8 bv = *(const s16x8*)(W2b + (size_t)(fc * 16 + (l & 15)) * 128 + kc * 32 + g * 8);
      acc2[fc] = __builtin_amdgcn_mfma_f32_16x16x32_bf16(e[kc], bv, acc2[fc], 0, 0, 0);
    }
  }

  float p[4] = {0.f, 0.f, 0.f, 0.f};
#pragma unroll
  for (int fc = 0; fc < 2; ++fc) {
    int col = fc * 16 + (l & 15);
    float wp = Wp[col], bb = b2[col];
#pragma unroll
    for (int reg = 0; reg < 4; ++reg)
      p[reg] += fmaxf(acc2[fc][reg] + bb, 0.f) * wp;
  }
#pragma unroll
  for (int reg = 0; reg < 4; ++reg) {
    p[reg] += __shfl_xor(p[reg], 1);
    p[reg] += __shfl_xor(p[reg], 2);
    p[reg] += __shfl_xor(p[reg], 4);
    p[reg] += __shfl_xor(p[reg], 8);
  }
  if ((l & 15) == 0) {
    float bb = bp[0];
#pragma unroll
    for (int reg = 0; reg < 4; ++reg) {
      int row = row0 + g * 4 + reg;
      if (row < L) out[row] = p[reg] + bb;
    }
  }
}

// ---------------- host launcher ----------------

extern "C" void kernel_launch(void* const* d_in, const int* in_sizes, int n_in,
                              void* d_out, int out_size, void* d_ws, size_t ws_size,
                              hipStream_t stream) {
  const float* x_virus = (const float*)d_in[0];
  const float* x_host  = (const float*)d_in[1];
  const int* src_vh = (const int*)d_in[2];
  const int* dst_vh = (const int*)d_in[3];
  const int* src_hv = (const int*)d_in[4];
  const int* dst_hv = (const int*)d_in[5];
  const int* lbl_v  = (const int*)d_in[6];
  const int* lbl_h  = (const int*)d_in[7];
  const float* Wrel[4] = {(const float*)d_in[8],  (const float*)d_in[11],
                          (const float*)d_in[14], (const float*)d_in[17]};
  const float* Wroot[4] = {(const float*)d_in[10], (const float*)d_in[13],
                           (const float*)d_in[16], (const float*)d_in[19]};
  const float* bias_c[4] = {(const float*)d_in[9], (const float*)d_in[12],
                            (const float*)d_in[15], (const float*)d_in[18]};
  const float* W1 = (const float*)d_in[20];
  const float* b1 = (const float*)d_in[21];
  const float* W2 = (const float*)d_in[22];
  const float* b2 = (const float*)d_in[23];
  const float* Wp = (const float*)d_in[24];
  const float* bp = (const float*)d_in[25];

  const int NV = in_sizes[0] / D;
  const int NH = in_sizes[1] / D;
  const int E  = in_sizes[2];
  const int L  = in_sizes[6];

  // ---- workspace carve-up ----
  char* ws = (char*)d_ws;
  size_t o = 0;
  auto balloc = [&](size_t nb) { char* p = ws + o; o += (nb + 255) & ~(size_t)255; return p; };
  unsigned short* xvb   = (unsigned short*)balloc((size_t)NV * D * 2);
  unsigned short* xhb   = (unsigned short*)balloc((size_t)NH * D * 2);
  unsigned short* xv1b  = (unsigned short*)balloc((size_t)NV * D * 2);
  unsigned short* Pvb   = (unsigned short*)balloc((size_t)NV * D * 2);
  unsigned short* xh1b  = (unsigned short*)balloc((size_t)NH * D * 2);
  unsigned short* Phb   = (unsigned short*)balloc((size_t)NH * D * 2);
  unsigned short* mean_v = (unsigned short*)balloc((size_t)NV * D * 2);
  unsigned short* mean_h = (unsigned short*)balloc((size_t)NH * D * 2);
  unsigned short* Wcat0 = (unsigned short*)balloc(128 * 256 * 2);
  unsigned short* Wcat1 = (unsigned short*)balloc(128 * 256 * 2);
  unsigned short* WcatFh = (unsigned short*)balloc(128 * 256 * 2);
  unsigned short* WcatFv = (unsigned short*)balloc(128 * 256 * 2);
  unsigned short* W2b = (unsigned short*)balloc(32 * 128 * 2);
  float* biasFh = (float*)balloc(128 * 4);
  float* biasFv = (float*)balloc(128 * 4);
  float* inv_v = (float*)balloc((size_t)NV * 4);
  int* cnt_v = (int*)balloc((size_t)NV * 4);
  int* off_v = (int*)balloc((size_t)NV * 4);
  int* csr_v = (int*)balloc((size_t)E * 4);
  int* histmat = (int*)balloc((size_t)512 * PGB * 4);
  int* histoff = (int*)balloc((size_t)512 * PGB * 4);
  int* histmatB = (int*)balloc((size_t)256 * PGB * 4);
  int* histoffB = (int*)balloc((size_t)256 * PGB * 4);
  unsigned* buf2E = (unsigned*)balloc((size_t)2 * E * 4);   // P0 [0,E) | binnedV [E,2E)
  unsigned* poolH = (unsigned*)balloc((size_t)E * 4);
  int* sums = (int*)balloc(512 * 4);

  auto cdiv = [](int a, int b) { return (a + b - 1) / b; };
  auto calc_shift = [](int n) { int s = 0; while ((1 << s) * 256 < n) ++s; return s; };

  // ---- sort A (merged): vh by src bucket, hv by dst bucket (both virus-id>>9) ----
  const int shiftV = calc_shift(NV);                 // 9
  const int nbinsA = cdiv(NV, 1 << shiftV);          // 196
  const int nbinsTot = 2 * nbinsA;
  const int nscA = nbinsTot * PGB;
  part_hist2_k<<<512, 256, 0, stream>>>(src_vh, dst_hv, histmat, E,
                                        nbinsA, nbinsA, shiftV);
  scan_chunk_k<<<cdiv(nscA, 1024), 256, 0, stream>>>(histmat, histoff, sums, nscA);
  scan_tops_k<<<1, 64, 0, stream>>>(sums, cdiv(nscA, 1024));
  scan_add_k<<<cdiv(nscA, 256), 256, 0, stream>>>(histoff, sums, nscA);
  part_scatter2_k<<<512, 256, 0, stream>>>(src_vh, dst_vh, src_hv, dst_hv,
                                           histoff, buf2E, E, nbinsA, nbinsA, shiftV);

  // ---- sort B: P0 (src-sorted vh edges) partitioned by host-dst bucket ----
  const int nbinsB = cdiv(NH, 128);                  // 157
  const int nscB = nbinsB * PGB;
  histB_k<<<PGB, 256, 0, stream>>>(buf2E, histmatB, E, nbinsB);
  scan_chunk_k<<<cdiv(nscB, 1024), 256, 0, stream>>>(histmatB, histoffB, sums, nscB);
  scan_tops_k<<<1, 64, 0, stream>>>(sums, cdiv(nscB, 1024));
  scan_add_k<<<cdiv(nscB, 256), 256, 0, stream>>>(histoffB, sums, nscB);
  scatB_k<<<PGB, 256, 0, stream>>>(buf2E, histoffB, poolH, E, nbinsB);

  // ---- CSR finalize for virus dsts ----
  csr_binV_k<<<nbinsA, 256, 0, stream>>>(buf2E, histoff, csr_v, off_v, cnt_v,
                                         inv_v, E, nbinsA, nbinsTot, NV);

  // ---- conversions + weight prep ----
  cvt_bf16_k<<<cdiv(NV * D / 4, 256), 256, 0, stream>>>(x_virus, xvb, NV * D / 4);
  cvt_bf16_k<<<cdiv(NH * D / 4, 256), 256, 0, stream>>>(x_host, xhb, NH * D / 4);
  pack_wcat_k<<<128, 256, 0, stream>>>(Wrel[0], Wroot[0], Wcat0);
  pack_wcat_k<<<128, 256, 0, stream>>>(Wrel[1], Wroot[1], Wcat1);
  fuse_w_k<<<128, 256, 0, stream>>>(W1, Wrel[2], Wroot[2], bias_c[2], nullptr, WcatFh, biasFh);
  fuse_w_k<<<128, 256, 0, stream>>>(W1, Wrel[3], Wroot[3], bias_c[3], b1, WcatFv, biasFv);
  cvt_bf16_k<<<cdiv(32 * 128 / 4, 256), 256, 0, stream>>>(W2, W2b, 32 * 128 / 4);

  const int nbv4 = cdiv(NV, 4);
  const int nbh64 = cdiv(NH, 64), nbv64 = cdiv(NV, 64);

  // ---- layer 0 (relu) ----
  bucket_agg_k<<<nbinsB, 256, 0, stream>>>(xvb, poolH, histoffB, mean_h, nbinsB, E, NH);
  agg1_k<<<nbv4, 256, 0, stream>>>(xhb, csr_v, off_v, cnt_v, inv_v, mean_v, NV);
  conv2_k<<<nbh64 + nbv64, 256, 0, stream>>>(
      mean_h, xhb, Wcat0, bias_c[0], xh1b, NH,
      mean_v, xvb, Wcat1, bias_c[1], xv1b, NV, nbh64, 1);

  // ---- layer 1 fused with W1 (no relu) ----
  bucket_agg_k<<<nbinsB, 256, 0, stream>>>(xv1b, poolH, histoffB, mean_h, nbinsB, E, NH);
  agg1_k<<<nbv4, 256, 0, stream>>>(xh1b, csr_v, off_v, cnt_v, inv_v, mean_v, NV);
  conv2_k<<<nbh64 + nbv64, 256, 0, stream>>>(
      mean_h, xh1b, WcatFh, biasFh, Phb, NH,
      mean_v, xv1b, WcatFv, biasFv, Pvb, NV, nbh64, 0);

  // ---- decoder ----
  dec2_k<<<cdiv(L, 64), 256, 0, stream>>>(Pvb, Phb, lbl_v, lbl_h, W2b, b2,
                                          Wp, bp, (float*)d_out, L);
}

// Round 13
// 3033.560 us; speedup vs baseline: 1.2636x; 1.2636x over previous
//
#include <hip/hip_runtime.h>

// GNN: 2-layer bipartite GraphConv + link decoder.
// Round 13: fix R12's serial bucket_agg -> wave-per-edge (lane l covers
// features l and l+64; 2 LDS ds_add_f32 per lane, 2-way bank = free),
// 32-dst buckets (625 blocks, 16.8KB LDS). Sort-B widened to 625 bins.
// Rest identical to R12 (passed correctness).

#define D 128
#define PGB 256   // partition blocks per side

typedef float f32x4 __attribute__((ext_vector_type(4)));
typedef short s16x8 __attribute__((ext_vector_type(8)));

__device__ __forceinline__ float lo16(unsigned u) { return __uint_as_float(u << 16); }
__device__ __forceinline__ float hi16(unsigned u) { return __uint_as_float(u & 0xffff0000u); }
__device__ __forceinline__ float b2f(unsigned short u) {
  return __uint_as_float(((unsigned)u) << 16);
}
__device__ __forceinline__ unsigned short pkb(float f) {
  unsigned b = __float_as_uint(f);
  return (unsigned short)((b + 0x7fffu + ((b >> 16) & 1u)) >> 16);
}
__device__ __forceinline__ unsigned pk2(float a, float b) {
  return (unsigned)pkb(a) | ((unsigned)pkb(b) << 16);
}

union U4S8 { uint4 u; s16x8 s; };

// ---------------- sort A (merged): vh edges by SRC bucket, hv edges by DST
// bucket — both key on virus-id>>9. side0 payload packs full (dst<<17)|src.

__global__ __launch_bounds__(256) void part_hist2_k(
    const int* __restrict__ key0, const int* __restrict__ key1,
    int* __restrict__ histmat, int E, int nbins0, int nbins1, int shift) {
  __shared__ int hist[256];
  const int t = threadIdx.x;
  const int side = blockIdx.x >> 8, blk = blockIdx.x & 255;
  const int* __restrict__ key = side ? key1 : key0;
  const int binbase = side ? nbins0 : 0;
  const int nbins = side ? nbins1 : nbins0;
  hist[t] = 0;
  __syncthreads();
  const int chunk = (E + PGB - 1) / PGB;
  const int e0 = blk * chunk, e1 = min(E, e0 + chunk);
  for (int i = e0 + t; i < e1; i += 256)
    atomicAdd(&hist[key[i] >> shift], 1);
  __syncthreads();
  if (t < nbins)
    histmat[(size_t)(binbase + t) * PGB + blk] = hist[t];
}

__global__ void scan_chunk_k(const int* __restrict__ in, int* __restrict__ out,
                             int* __restrict__ sums, int n) {
  __shared__ int lds[256];
  int t = threadIdx.x;
  int base = blockIdx.x * 1024 + t * 4;
  int v0 = (base + 0 < n) ? in[base + 0] : 0;
  int v1 = (base + 1 < n) ? in[base + 1] : 0;
  int v2 = (base + 2 < n) ? in[base + 2] : 0;
  int v3 = (base + 3 < n) ? in[base + 3] : 0;
  int s = v0 + v1 + v2 + v3;
  lds[t] = s;
  __syncthreads();
  for (int off = 1; off < 256; off <<= 1) {
    int x = (t >= off) ? lds[t - off] : 0;
    __syncthreads();
    lds[t] += x;
    __syncthreads();
  }
  int excl = lds[t] - s;
  if (t == 255) sums[blockIdx.x] = lds[255];
  if (base + 0 < n) out[base + 0] = excl; excl += v0;
  if (base + 1 < n) out[base + 1] = excl; excl += v1;
  if (base + 2 < n) out[base + 2] = excl; excl += v2;
  if (base + 3 < n) out[base + 3] = excl;
}

__global__ void scan_tops_k(int* __restrict__ sums, int nb) {
  if (threadIdx.x == 0 && blockIdx.x == 0) {
    int run = 0;
    for (int i = 0; i < nb; ++i) { int x = sums[i]; sums[i] = run; run += x; }
  }
}

__global__ void scan_add_k(int* __restrict__ out, const int* __restrict__ sums, int n) {
  int i = blockIdx.x * 256 + threadIdx.x;
  if (i < n) out[i] += sums[i >> 10];
}

__global__ __launch_bounds__(256) void part_scatter2_k(
    const int* __restrict__ src0, const int* __restrict__ dst0,
    const int* __restrict__ src1, const int* __restrict__ dst1,
    const int* __restrict__ histoff, unsigned* __restrict__ out,
    int E, int nbins0, int nbins1, int shift) {
  __shared__ int cur[256];
  const int t = threadIdx.x;
  const int side = blockIdx.x >> 8, blk = blockIdx.x & 255;
  const int binbase = side ? nbins0 : 0;
  const int nbins = side ? nbins1 : nbins0;
  if (t < nbins) cur[t] = histoff[(size_t)(binbase + t) * PGB + blk];
  __syncthreads();
  const int chunk = (E + PGB - 1) / PGB;
  const int e0 = blk * chunk, e1 = min(E, e0 + chunk);
  const int mask = (1 << shift) - 1;
  for (int i = e0 + t; i < e1; i += 256) {
    int b; unsigned pk;
    if (side) {
      int d = dst1[i], s = src1[i];
      b = d >> shift;
      pk = ((unsigned)(d & mask) << 17) | (unsigned)s;
    } else {
      int d = dst0[i], s = src0[i];
      b = s >> shift;                       // key = SRC bucket
      pk = ((unsigned)d << 17) | (unsigned)s;  // full dst(15b) | src(17b)
    }
    int p = atomicAdd(&cur[b], 1);   // LDS atomic
    out[p] = pk;
  }
}

// ---------------- sort B: src-sorted P0 stream partitioned by 32-dst bucket ----
// P0 entry u = (dst<<17)|src; bucket = dst>>5 = u>>22 (625 bins).
// Pool keeps (dst&31)<<17 | src = u & 0x3FFFFF.

__global__ __launch_bounds__(256) void histB_k(
    const unsigned* __restrict__ P, int* __restrict__ histmat, int E, int nbins) {
  __shared__ int hist[640];
  const int t = threadIdx.x, blk = blockIdx.x;
  for (int i = t; i < 640; i += 256) hist[i] = 0;
  __syncthreads();
  const int chunk = (E + PGB - 1) / PGB;
  const int e0 = blk * chunk, e1 = min(E, e0 + chunk);
  for (int i = e0 + t; i < e1; i += 256)
    atomicAdd(&hist[P[i] >> 22], 1);
  __syncthreads();
  for (int b = t; b < nbins; b += 256)
    histmat[(size_t)b * PGB + blk] = hist[b];
}

__global__ __launch_bounds__(256) void scatB_k(
    const unsigned* __restrict__ P, const int* __restrict__ histoff,
    unsigned* __restrict__ pool, int E, int nbins) {
  __shared__ int cur[640];
  const int t = threadIdx.x, blk = blockIdx.x;
  for (int b = t; b < nbins; b += 256)
    cur[b] = histoff[(size_t)b * PGB + blk];
  __syncthreads();
  const int chunk = (E + PGB - 1) / PGB;
  const int e0 = blk * chunk, e1 = min(E, e0 + chunk);
  for (int i = e0 + t; i < e1; i += 256) {
    unsigned u = P[i];
    int p = atomicAdd(&cur[u >> 22], 1);   // LDS atomic
    pool[p] = u & 0x3FFFFFu;
  }
}

// ---------------- CSR finalize for virus dsts (side1 of sort A) ----------------

__global__ __launch_bounds__(256) void csr_binV_k(
    const unsigned* __restrict__ binned, const int* __restrict__ histoff,
    int* __restrict__ csr, int* __restrict__ off, int* __restrict__ cnt,
    float* __restrict__ inv, int E, int nbins0, int nbinsTot, int N) {
  __shared__ int lcnt[512], lex[512], tmp[256];
  const int t = threadIdx.x;
  const int bin = blockIdx.x + nbins0;   // global bin (side1 range)
  const int lb = blockIdx.x;
  const int e0 = histoff[(size_t)bin * PGB];
  const int e1 = (bin + 1 < nbinsTot) ? histoff[(size_t)(bin + 1) * PGB] : 2 * E;
  lcnt[t] = 0; lcnt[t + 256] = 0;
  __syncthreads();
  for (int i = e0 + t; i < e1; i += 256)
    atomicAdd(&lcnt[binned[i] >> 17], 1);   // LDS atomic
  __syncthreads();
  int a = lcnt[t], b = lcnt[t + 256];
  tmp[t] = a; __syncthreads();
  for (int o = 1; o < 256; o <<= 1) {
    int x = (t >= o) ? tmp[t - o] : 0;
    __syncthreads(); tmp[t] += x; __syncthreads();
  }
  int inclA = tmp[t], totA = tmp[255];
  __syncthreads();
  tmp[t] = b; __syncthreads();
  for (int o = 1; o < 256; o <<= 1) {
    int x = (t >= o) ? tmp[t - o] : 0;
    __syncthreads(); tmp[t] += x; __syncthreads();
  }
  int inclB = tmp[t];
  lex[t] = inclA - a;
  lex[t + 256] = totA + inclB - b;
  __syncthreads();
  const int based = lb << 9;
  const int nd = min(512, N - based);
  for (int dl = t; dl < nd; dl += 256) {
    int c = lcnt[dl];
    off[based + dl] = e0 - E + lex[dl];
    cnt[based + dl] = c;
    inv[based + dl] = 1.0f / fmaxf((float)c, 1.0f);
  }
  __syncthreads();
  lcnt[t] = lex[t]; lcnt[t + 256] = lex[t + 256];
  __syncthreads();
  for (int i = e0 + t; i < e1; i += 256) {
    unsigned u = binned[i];
    int dl = (int)(u >> 17);
    int p = atomicAdd(&lcnt[dl], 1);   // LDS atomic
    csr[e0 - E + p] = (int)(u & 0x1FFFFu);
  }
}

// ---------------- conversions / weight prep ----------------

__global__ void cvt_bf16_k(const float* __restrict__ in, unsigned short* __restrict__ out, int n4) {
  int i = blockIdx.x * 256 + threadIdx.x;
  if (i < n4) {
    float4 v = ((const float4*)in)[i];
    ushort4 o;
    o.x = pkb(v.x); o.y = pkb(v.y); o.z = pkb(v.z); o.w = pkb(v.w);
    ((ushort4*)out)[i] = o;
  }
}

__global__ void pack_wcat_k(const float* __restrict__ Wrel, const float* __restrict__ Wroot,
                            unsigned short* __restrict__ Wcat) {
  int idx = blockIdx.x * 256 + threadIdx.x;  // 32768
  int n = idx >> 8, k = idx & 255;
  float v = (k < 128) ? Wrel[(n << 7) + k] : Wroot[(n << 7) + k - 128];
  Wcat[idx] = pkb(v);
}

__global__ __launch_bounds__(256) void fuse_w_k(
    const float* __restrict__ W1, const float* __restrict__ Wrel,
    const float* __restrict__ Wroot, const float* __restrict__ brel,
    const float* __restrict__ b1, unsigned short* __restrict__ Wf,
    float* __restrict__ biasF) {
  const int i = blockIdx.x;
  const int kk = threadIdx.x;
  const float* __restrict__ Wsrc = (kk < 128) ? Wrel : Wroot;
  const int k = kk & 127;
  float s = 0.f;
  for (int o = 0; o < 128; ++o)
    s += W1[i * 128 + o] * Wsrc[o * 128 + k];
  Wf[i * 256 + kk] = pkb(s);
  if (kk == 0) {
    float sb = b1 ? b1[i] : 0.f;
    for (int o = 0; o < 128; ++o) sb += W1[i * 128 + o] * brel[o];
    biasF[i] = sb;
  }
}

// ---------------- host-side bucket aggregation (src-swept, wave-per-edge) ----
// One block per 32-dst bucket; 4 waves, each wave owns one edge at a time
// (2 in flight). Lane l covers features l and l+64: two coalesced 128B
// loads + two LDS ds_add_f32 (bank (2*dl+l)%32 -> 2-way = free).

__global__ __launch_bounds__(256) void bucket_agg_k(
    const unsigned short* __restrict__ xsrc, const unsigned* __restrict__ pool,
    const int* __restrict__ histoffB, unsigned short* __restrict__ mean,
    int nbins, int E, int N) {
  __shared__ float accs[32 * 130];
  __shared__ int cnts[32];
  const int t = threadIdx.x;
  const int l = t & 63, wv = t >> 6;
  const int bin = blockIdx.x;
  const int e0 = histoffB[(size_t)bin * PGB];
  const int e1 = (bin + 1 < nbins) ? histoffB[(size_t)(bin + 1) * PGB] : E;
  for (int i = t; i < 32 * 130; i += 256) accs[i] = 0.f;
  if (t < 32) cnts[t] = 0;
  __syncthreads();

  for (int ed = e0 + wv * 2; ed < e1; ed += 8) {
    unsigned u0 = pool[ed];
    const bool has1 = (ed + 1) < e1;
    unsigned u1 = has1 ? pool[ed + 1] : 0;
    const int dl0 = (int)(u0 >> 17), dl1 = (int)(u1 >> 17);
    const unsigned short* __restrict__ r0 = xsrc + (size_t)(u0 & 0x1FFFFu) * 128;
    const unsigned short* __restrict__ r1 = xsrc + (size_t)(u1 & 0x1FFFFu) * 128;
    unsigned short a0 = r0[l], b0 = r0[l + 64];
    unsigned short a1 = 0, b1 = 0;
    if (has1) { a1 = r1[l]; b1 = r1[l + 64]; }
    atomicAdd(&accs[dl0 * 130 + l], b2f(a0));
    atomicAdd(&accs[dl0 * 130 + l + 64], b2f(b0));
    if (l == 0) atomicAdd(&cnts[dl0], 1);
    if (has1) {
      atomicAdd(&accs[dl1 * 130 + l], b2f(a1));
      atomicAdd(&accs[dl1 * 130 + l + 64], b2f(b1));
      if (l == 0) atomicAdd(&cnts[dl1], 1);
    }
  }
  __syncthreads();

  const int based = bin << 5;
  for (int idx = t; idx < 32 * 128; idx += 256) {
    int dl = idx >> 7, e = idx & 127;
    int row = based + dl;
    if (row < N) {
      float iv = 1.0f / fmaxf((float)cnts[dl], 1.f);
      mean[(size_t)row * 128 + e] = pkb(accs[dl * 130 + e] * iv);
    }
  }
}

// ---------------- virus-side aggregation: one wave/dst, 16 in flight ----------------

__global__ __launch_bounds__(256) void agg1_k(
    const unsigned short* __restrict__ xsrc, const int* __restrict__ csr,
    const int* __restrict__ off, const int* __restrict__ cnt,
    const float* __restrict__ inv, unsigned short* __restrict__ mean, int ndst) {
  int wid = blockIdx.x * 4 + (threadIdx.x >> 6);
  int lane = threadIdx.x & 63;
  if (wid >= ndst) return;
  int o = off[wid], deg = cnt[wid];
  int q = lane >> 4, sl = lane & 15;
  float acc[8] = {0.f, 0.f, 0.f, 0.f, 0.f, 0.f, 0.f, 0.f};
  int sN[4];
#pragma unroll
  for (int j = 0; j < 4; ++j) {
    int e = j * 4 + q;
    sN[j] = (e < deg) ? csr[o + e] : -1;
  }
  for (int i = 0; i < deg; i += 16) {
    int cu[4];
#pragma unroll
    for (int j = 0; j < 4; ++j) {
      cu[j] = sN[j];
      int e = i + 16 + j * 4 + q;
      sN[j] = (e < deg) ? csr[o + e] : -1;
    }
    uint4 v[4];
#pragma unroll
    for (int j = 0; j < 4; ++j)
      if (cu[j] >= 0) v[j] = *(const uint4*)(xsrc + (size_t)cu[j] * 128 + sl * 8);
#pragma unroll
    for (int j = 0; j < 4; ++j) {
      if (cu[j] >= 0) {
        acc[0] += lo16(v[j].x); acc[1] += hi16(v[j].x);
        acc[2] += lo16(v[j].y); acc[3] += hi16(v[j].y);
        acc[4] += lo16(v[j].z); acc[5] += hi16(v[j].z);
        acc[6] += lo16(v[j].w); acc[7] += hi16(v[j].w);
      }
    }
  }
#pragma unroll
  for (int j = 0; j < 8; ++j) {
    acc[j] += __shfl_xor(acc[j], 16);
    acc[j] += __shfl_xor(acc[j], 32);
  }
  if (q == 0) {
    float iv = inv[wid];
    uint4 r;
    r.x = pk2(acc[0] * iv, acc[1] * iv);
    r.y = pk2(acc[2] * iv, acc[3] * iv);
    r.z = pk2(acc[4] * iv, acc[5] * iv);
    r.w = pk2(acc[6] * iv, acc[7] * iv);
    *(uint4*)(mean + (size_t)wid * 128 + sl * 8) = r;
  }
}

// ---------------- merged conv GEMM (both sides), 64 rows/block ----------------

__global__ __launch_bounds__(256) void conv2_k(
    const unsigned short* __restrict__ A1a, const unsigned short* __restrict__ A2a,
    const unsigned short* __restrict__ Wa, const float* __restrict__ ba,
    unsigned short* __restrict__ outa, int na,
    const unsigned short* __restrict__ A1b, const unsigned short* __restrict__ A2b,
    const unsigned short* __restrict__ Wb, const float* __restrict__ bb_,
    unsigned short* __restrict__ outb, int nb, int nblk0, int relu) {
  int blk = blockIdx.x;
  const unsigned short *A1, *A2, *W;
  const float* bias; unsigned short* out; int n;
  if (blk < nblk0) { A1 = A1a; A2 = A2a; W = Wa; bias = ba; out = outa; n = na; }
  else { blk -= nblk0; A1 = A1b; A2 = A2b; W = Wb; bias = bb_; out = outb; n = nb; }

  const int t = threadIdx.x;
  const int l = t & 63, wv = t >> 6;
  const int g = l >> 4;
  const int row0 = blk * 64 + wv * 16;
  int r = row0 + (l & 15); r = r < n ? r : n - 1;

  s16x8 av[8];
#pragma unroll
  for (int c = 0; c < 4; ++c)
    av[c] = *(const s16x8*)(A1 + (size_t)r * 128 + c * 32 + g * 8);
#pragma unroll
  for (int c = 0; c < 4; ++c)
    av[4 + c] = *(const s16x8*)(A2 + (size_t)r * 128 + c * 32 + g * 8);

  f32x4 acc[8] = {};
#pragma unroll
  for (int ch = 0; ch < 8; ++ch) {
#pragma unroll
    for (int fc = 0; fc < 8; ++fc) {
      s16x8 bv = *(const s16x8*)(W + (size_t)(fc * 16 + (l & 15)) * 256 + ch * 32 + g * 8);
      acc[fc] = __builtin_amdgcn_mfma_f32_16x16x32_bf16(av[ch], bv, acc[fc], 0, 0, 0);
    }
  }

#pragma unroll
  for (int fc = 0; fc < 8; ++fc) {
    int col = fc * 16 + (l & 15);
    float bv = bias[col];
    int rbase = row0 + g * 4;
#pragma unroll
    for (int reg = 0; reg < 4; ++reg) {
      int row = rbase + reg;
      if (row < n) {
        float v = acc[fc][reg] + bv;
        if (relu) v = fmaxf(v, 0.f);
        out[(size_t)row * 128 + col] = pkb(v);
      }
    }
  }
}

// ---------------- decoder: h1 = relu(Pv[lv]-Ph[lh]); stage2 MFMA; dot ----------

__global__ __launch_bounds__(256) void dec2_k(
    const unsigned short* __restrict__ Pv, const unsigned short* __restrict__ Ph,
    const int* __restrict__ lv, const int* __restrict__ lh,
    const unsigned short* __restrict__ W2b, const float* __restrict__ b2,
    const float* __restrict__ Wp, const float* __restrict__ bp,
    float* __restrict__ out, int L) {
  const int t = threadIdx.x;
  const int l = t & 63, wv = t >> 6;
  const int g = l >> 4;
  const int row0 = blockIdx.x * 64 + wv * 16;

  int rowc = row0 + (l & 15);
  rowc = rowc < L ? rowc : L - 1;
  const int iv = lv[rowc], ih = lh[rowc];
  const unsigned short* __restrict__ pv = Pv + (size_t)iv * 128 + g * 8;
  const unsigned short* __restrict__ ph = Ph + (size_t)ih * 128 + g * 8;

  uint4 A[4], B[4];
#pragma unroll
  for (int ch = 0; ch < 4; ++ch) A[ch] = *(const uint4*)(pv + ch * 32);
#pragma unroll
  for (int ch = 0; ch < 4; ++ch) B[ch] = *(const uint4*)(ph + ch * 32);

  s16x8 e[4];
#pragma unroll
  for (int ch = 0; ch < 4; ++ch) {
    U4S8 u;
    u.u.x = pk2(fmaxf(lo16(A[ch].x) - lo16(B[ch].x), 0.f), fmaxf(hi16(A[ch].x) - hi16(B[ch].x), 0.f));
    u.u.y = pk2(fmaxf(lo16(A[ch].y) - lo16(B[ch].y), 0.f), fmaxf(hi16(A[ch].y) - hi16(B[ch].y), 0.f));
    u.u.z = pk2(fmaxf(lo16(A[ch].z) - lo16(B[ch].z), 0.f), fmaxf(hi16(A[ch].z) - hi16(B[ch].z), 0.f));
    u.u.w = pk2(fmaxf(lo16(A[ch].w) - lo16(B[ch].w), 0.f), fmaxf(hi16(A[ch].w) - hi16(B[ch].w), 0.f));
    e[ch] = u.s;
  }

  f32x4 acc2[2] = {};
#pragma unroll
  for (int kc = 0; kc < 4; ++kc) {
#pragma unroll
    for (int fc = 0; fc < 2; ++fc) {
      s16x8 bv = *(const s16x8*)(W2b + (size_t)(fc * 16 + (l & 15)) * 128 + kc * 32 + g * 8);
      acc2[fc] = __builtin_amdgcn_mfma_f32_16x16x32_bf16(e[kc], bv, acc2[fc], 0, 0, 0);
    }
  }

  float p[4] = {0.f, 0.f, 0.f, 0.f};
#pragma unroll
  for (int fc = 0; fc < 2; ++fc) {
    int col = fc * 16 + (l & 15);
    float wp = Wp[col], bb = b2[col];
#pragma unroll
    for (int reg = 0; reg < 4; ++reg)
      p[reg] += fmaxf(acc2[fc][reg] + bb, 0.f) * wp;
  }
#pragma unroll
  for (int reg = 0; reg < 4; ++reg) {
    p[reg] += __shfl_xor(p[reg], 1);
    p[reg] += __shfl_xor(p[reg], 2);
    p[reg] += __shfl_xor(p[reg], 4);
    p[reg] += __shfl_xor(p[reg], 8);
  }
  if ((l & 15) == 0) {
    float bb = bp[0];
#pragma unroll
    for (int reg = 0; reg < 4; ++reg) {
      int row = row0 + g * 4 + reg;
      if (row < L) out[row] = p[reg] + bb;
    }
  }
}

// ---------------- host launcher ----------------

extern "C" void kernel_launch(void* const* d_in, const int* in_sizes, int n_in,
                              void* d_out, int out_size, void* d_ws, size_t ws_size,
                              hipStream_t stream) {
  const float* x_virus = (const float*)d_in[0];
  const float* x_host  = (const float*)d_in[1];
  const int* src_vh = (const int*)d_in[2];
  const int* dst_vh = (const int*)d_in[3];
  const int* src_hv = (const int*)d_in[4];
  const int* dst_hv = (const int*)d_in[5];
  const int* lbl_v  = (const int*)d_in[6];
  const int* lbl_h  = (const int*)d_in[7];
  const float* Wrel[4] = {(const float*)d_in[8],  (const float*)d_in[11],
                          (const float*)d_in[14], (const float*)d_in[17]};
  const float* Wroot[4] = {(const float*)d_in[10], (const float*)d_in[13],
                           (const float*)d_in[16], (const float*)d_in[19]};
  const float* bias_c[4] = {(const float*)d_in[9], (const float*)d_in[12],
                            (const float*)d_in[15], (const float*)d_in[18]};
  const float* W1 = (const float*)d_in[20];
  const float* b1 = (const float*)d_in[21];
  const float* W2 = (const float*)d_in[22];
  const float* b2 = (const float*)d_in[23];
  const float* Wp = (const float*)d_in[24];
  const float* bp = (const float*)d_in[25];

  const int NV = in_sizes[0] / D;
  const int NH = in_sizes[1] / D;
  const int E  = in_sizes[2];
  const int L  = in_sizes[6];

  // ---- workspace carve-up ----
  char* ws = (char*)d_ws;
  size_t o = 0;
  auto balloc = [&](size_t nb) { char* p = ws + o; o += (nb + 255) & ~(size_t)255; return p; };
  unsigned short* xvb   = (unsigned short*)balloc((size_t)NV * D * 2);
  unsigned short* xhb   = (unsigned short*)balloc((size_t)NH * D * 2);
  unsigned short* xv1b  = (unsigned short*)balloc((size_t)NV * D * 2);
  unsigned short* Pvb   = (unsigned short*)balloc((size_t)NV * D * 2);
  unsigned short* xh1b  = (unsigned short*)balloc((size_t)NH * D * 2);
  unsigned short* Phb   = (unsigned short*)balloc((size_t)NH * D * 2);
  unsigned short* mean_v = (unsigned short*)balloc((size_t)NV * D * 2);
  unsigned short* mean_h = (unsigned short*)balloc((size_t)NH * D * 2);
  unsigned short* Wcat0 = (unsigned short*)balloc(128 * 256 * 2);
  unsigned short* Wcat1 = (unsigned short*)balloc(128 * 256 * 2);
  unsigned short* WcatFh = (unsigned short*)balloc(128 * 256 * 2);
  unsigned short* WcatFv = (unsigned short*)balloc(128 * 256 * 2);
  unsigned short* W2b = (unsigned short*)balloc(32 * 128 * 2);
  float* biasFh = (float*)balloc(128 * 4);
  float* biasFv = (float*)balloc(128 * 4);
  float* inv_v = (float*)balloc((size_t)NV * 4);
  int* cnt_v = (int*)balloc((size_t)NV * 4);
  int* off_v = (int*)balloc((size_t)NV * 4);
  int* csr_v = (int*)balloc((size_t)E * 4);
  int* histmat = (int*)balloc((size_t)512 * PGB * 4);
  int* histoff = (int*)balloc((size_t)512 * PGB * 4);
  int* histmatB = (int*)balloc((size_t)640 * PGB * 4);
  int* histoffB = (int*)balloc((size_t)640 * PGB * 4);
  unsigned* buf2E = (unsigned*)balloc((size_t)2 * E * 4);   // P0 [0,E) | binnedV [E,2E)
  unsigned* poolH = (unsigned*)balloc((size_t)E * 4);
  int* sums = (int*)balloc(512 * 4);

  auto cdiv = [](int a, int b) { return (a + b - 1) / b; };
  auto calc_shift = [](int n) { int s = 0; while ((1 << s) * 256 < n) ++s; return s; };

  // ---- sort A (merged): vh by src bucket, hv by dst bucket (both virus-id>>9) ----
  const int shiftV = calc_shift(NV);                 // 9
  const int nbinsA = cdiv(NV, 1 << shiftV);          // 196
  const int nbinsTot = 2 * nbinsA;
  const int nscA = nbinsTot * PGB;
  part_hist2_k<<<512, 256, 0, stream>>>(src_vh, dst_hv, histmat, E,
                                        nbinsA, nbinsA, shiftV);
  scan_chunk_k<<<cdiv(nscA, 1024), 256, 0, stream>>>(histmat, histoff, sums, nscA);
  scan_tops_k<<<1, 64, 0, stream>>>(sums, cdiv(nscA, 1024));
  scan_add_k<<<cdiv(nscA, 256), 256, 0, stream>>>(histoff, sums, nscA);
  part_scatter2_k<<<512, 256, 0, stream>>>(src_vh, dst_vh, src_hv, dst_hv,
                                           histoff, buf2E, E, nbinsA, nbinsA, shiftV);

  // ---- sort B: P0 (src-sorted vh edges) partitioned by 32-dst bucket ----
  const int nbinsB = cdiv(NH, 32);                   // 625
  const int nscB = nbinsB * PGB;
  histB_k<<<PGB, 256, 0, stream>>>(buf2E, histmatB, E, nbinsB);
  scan_chunk_k<<<cdiv(nscB, 1024), 256, 0, stream>>>(histmatB, histoffB, sums, nscB);
  scan_tops_k<<<1, 64, 0, stream>>>(sums, cdiv(nscB, 1024));
  scan_add_k<<<cdiv(nscB, 256), 256, 0, stream>>>(histoffB, sums, nscB);
  scatB_k<<<PGB, 256, 0, stream>>>(buf2E, histoffB, poolH, E, nbinsB);

  // ---- CSR finalize for virus dsts ----
  csr_binV_k<<<nbinsA, 256, 0, stream>>>(buf2E, histoff, csr_v, off_v, cnt_v,
                                         inv_v, E, nbinsA, nbinsTot, NV);

  // ---- conversions + weight prep ----
  cvt_bf16_k<<<cdiv(NV * D / 4, 256), 256, 0, stream>>>(x_virus, xvb, NV * D / 4);
  cvt_bf16_k<<<cdiv(NH * D / 4, 256), 256, 0, stream>>>(x_host, xhb, NH * D / 4);
  pack_wcat_k<<<128, 256, 0, stream>>>(Wrel[0], Wroot[0], Wcat0);
  pack_wcat_k<<<128, 256, 0, stream>>>(Wrel[1], Wroot[1], Wcat1);
  fuse_w_k<<<128, 256, 0, stream>>>(W1, Wrel[2], Wroot[2], bias_c[2], nullptr, WcatFh, biasFh);
  fuse_w_k<<<128, 256, 0, stream>>>(W1, Wrel[3], Wroot[3], bias_c[3], b1, WcatFv, biasFv);
  cvt_bf16_k<<<cdiv(32 * 128 / 4, 256), 256, 0, stream>>>(W2, W2b, 32 * 128 / 4);

  const int nbv4 = cdiv(NV, 4);
  const int nbh64 = cdiv(NH, 64), nbv64 = cdiv(NV, 64);

  // ---- layer 0 (relu) ----
  bucket_agg_k<<<nbinsB, 256, 0, stream>>>(xvb, poolH, histoffB, mean_h, nbinsB, E, NH);
  agg1_k<<<nbv4, 256, 0, stream>>>(xhb, csr_v, off_v, cnt_v, inv_v, mean_v, NV);
  conv2_k<<<nbh64 + nbv64, 256, 0, stream>>>(
      mean_h, xhb, Wcat0, bias_c[0], xh1b, NH,
      mean_v, xvb, Wcat1, bias_c[1], xv1b, NV, nbh64, 1);

  // ---- layer 1 fused with W1 (no relu) ----
  bucket_agg_k<<<nbinsB, 256, 0, stream>>>(xv1b, poolH, histoffB, mean_h, nbinsB, E, NH);
  agg1_k<<<nbv4, 256, 0, stream>>>(xh1b, csr_v, off_v, cnt_v, inv_v, mean_v, NV);
  conv2_k<<<nbh64 + nbv64, 256, 0, stream>>>(
      mean_h, xh1b, WcatFh, biasFh, Phb, NH,
      mean_v, xv1b, WcatFv, biasFv, Pvb, NV, nbh64, 0);

  // ---- decoder ----
  dec2_k<<<cdiv(L, 64), 256, 0, stream>>>(Pvb, Phb, lbl_v, lbl_h, W2b, b2,
                                          Wp, bp, (float*)d_out, L);
}

// Round 14
// 459.712 us; speedup vs baseline: 8.3384x; 6.5988x over previous
//
#include <hip/hip_runtime.h>

// GNN: 2-layer bipartite GraphConv + link decoder.
// Round 14: revert to R10 structure (best: 478us; R12/R13 src-sweep branch
// abandoned - bucket agg loses 10x TLP, gather at ~8.4TB/s L2+L3 is the
// right form). Polish: parallel tops-scan (was single-thread serial),
// prep kernels merged 7->2 dispatches.

#define D 128
#define PGB 256   // partition blocks per side

typedef float f32x4 __attribute__((ext_vector_type(4)));
typedef short s16x8 __attribute__((ext_vector_type(8)));

__device__ __forceinline__ float lo16(unsigned u) { return __uint_as_float(u << 16); }
__device__ __forceinline__ float hi16(unsigned u) { return __uint_as_float(u & 0xffff0000u); }
__device__ __forceinline__ unsigned short pkb(float f) {
  unsigned b = __float_as_uint(f);
  return (unsigned short)((b + 0x7fffu + ((b >> 16) & 1u)) >> 16);
}
__device__ __forceinline__ unsigned pk2(float a, float b) {
  return (unsigned)pkb(a) | ((unsigned)pkb(b) << 16);
}

union U4S8 { uint4 u; s16x8 s; };

// ---------------- CSR build: merged 2-side counting-sort ----------------

__global__ __launch_bounds__(256) void part_hist2_k(
    const int* __restrict__ dst0, const int* __restrict__ dst1,
    int* __restrict__ histmat, int E, int nbins0, int nbins1,
    int shift0, int shift1) {
  __shared__ int hist[256];
  const int t = threadIdx.x;
  const int side = blockIdx.x >> 8, blk = blockIdx.x & 255;
  const int* __restrict__ dst = side ? dst1 : dst0;
  const int shift = side ? shift1 : shift0;
  const int binbase = side ? nbins0 : 0;
  const int nbins = side ? nbins1 : nbins0;
  hist[t] = 0;
  __syncthreads();
  const int chunk = (E + PGB - 1) / PGB;
  const int e0 = blk * chunk, e1 = min(E, e0 + chunk);
  for (int i = e0 + t; i < e1; i += 256)
    atomicAdd(&hist[dst[i] >> shift], 1);
  __syncthreads();
  if (t < nbins)   // GUARD: each histmat row written by exactly one side
    histmat[(size_t)(binbase + t) * PGB + blk] = hist[t];
}

__global__ void scan_chunk_k(const int* __restrict__ in, int* __restrict__ out,
                             int* __restrict__ sums, int n) {
  __shared__ int lds[256];
  int t = threadIdx.x;
  int base = blockIdx.x * 1024 + t * 4;
  int v0 = (base + 0 < n) ? in[base + 0] : 0;
  int v1 = (base + 1 < n) ? in[base + 1] : 0;
  int v2 = (base + 2 < n) ? in[base + 2] : 0;
  int v3 = (base + 3 < n) ? in[base + 3] : 0;
  int s = v0 + v1 + v2 + v3;
  lds[t] = s;
  __syncthreads();
  for (int off = 1; off < 256; off <<= 1) {
    int x = (t >= off) ? lds[t - off] : 0;
    __syncthreads();
    lds[t] += x;
    __syncthreads();
  }
  int excl = lds[t] - s;
  if (t == 255) sums[blockIdx.x] = lds[255];
  if (base + 0 < n) out[base + 0] = excl; excl += v0;
  if (base + 1 < n) out[base + 1] = excl; excl += v1;
  if (base + 2 < n) out[base + 2] = excl; excl += v2;
  if (base + 3 < n) out[base + 3] = excl;
}

// parallel exclusive scan of the per-chunk totals (nb <= 256)
__global__ void scan_tops_k(int* __restrict__ sums, int nb) {
  __shared__ int lds[256];
  int t = threadIdx.x;
  int v = (t < nb) ? sums[t] : 0;
  lds[t] = v;
  __syncthreads();
  for (int off = 1; off < 256; off <<= 1) {
    int x = (t >= off) ? lds[t - off] : 0;
    __syncthreads();
    lds[t] += x;
    __syncthreads();
  }
  if (t < nb) sums[t] = lds[t] - v;
}

__global__ void scan_add_k(int* __restrict__ out, const int* __restrict__ sums, int n) {
  int i = blockIdx.x * 256 + threadIdx.x;
  if (i < n) out[i] += sums[i >> 10];
}

__global__ __launch_bounds__(256) void part_scatter2_k(
    const int* __restrict__ src0, const int* __restrict__ dst0,
    const int* __restrict__ src1, const int* __restrict__ dst1,
    const int* __restrict__ histoff, unsigned* __restrict__ binned,
    int E, int nbins0, int nbins1, int shift0, int shift1) {
  __shared__ int cur[256];
  const int t = threadIdx.x;
  const int side = blockIdx.x >> 8, blk = blockIdx.x & 255;
  const int* __restrict__ src = side ? src1 : src0;
  const int* __restrict__ dst = side ? dst1 : dst0;
  const int shift = side ? shift1 : shift0;
  const int binbase = side ? nbins0 : 0;
  const int nbins = side ? nbins1 : nbins0;
  if (t < nbins) cur[t] = histoff[(size_t)(binbase + t) * PGB + blk];
  __syncthreads();
  const int chunk = (E + PGB - 1) / PGB;
  const int e0 = blk * chunk, e1 = min(E, e0 + chunk);
  const int mask = (1 << shift) - 1;
  for (int i = e0 + t; i < e1; i += 256) {
    int d = dst[i], s = src[i];
    int b = d >> shift;
    int p = atomicAdd(&cur[b], 1);   // LDS atomic
    binned[p] = ((unsigned)(d & mask) << 17) | (unsigned)s;
  }
}

__global__ __launch_bounds__(256) void csr_bin2_k(
    const unsigned* __restrict__ binned, const int* __restrict__ histoff,
    int* __restrict__ csr0, int* __restrict__ off0, int* __restrict__ cnt0, float* __restrict__ inv0,
    int* __restrict__ csr1, int* __restrict__ off1, int* __restrict__ cnt1, float* __restrict__ inv1,
    int E, int nbins0, int nbinsTot, int shift0, int shift1, int N0, int N1) {
  __shared__ int lcnt[512], lex[512], tmp[256];
  const int t = threadIdx.x, bin = blockIdx.x;
  const int side = (bin >= nbins0);
  const int lb = side ? bin - nbins0 : bin;
  const int shift = side ? shift1 : shift0;
  const int N = side ? N1 : N0;
  const int ebase = side ? E : 0;
  int* __restrict__ csr = side ? csr1 : csr0;
  int* __restrict__ off = side ? off1 : off0;
  int* __restrict__ cnt = side ? cnt1 : cnt0;
  float* __restrict__ inv = side ? inv1 : inv0;
  const int bw = 1 << shift;
  const int e0 = histoff[(size_t)bin * PGB];
  const int e1 = (bin + 1 < nbinsTot) ? histoff[(size_t)(bin + 1) * PGB] : 2 * E;
  lcnt[t] = 0; lcnt[t + 256] = 0;
  __syncthreads();
  for (int i = e0 + t; i < e1; i += 256)
    atomicAdd(&lcnt[binned[i] >> 17], 1);   // LDS atomic
  __syncthreads();
  int a = lcnt[t], b = lcnt[t + 256];
  tmp[t] = a; __syncthreads();
  for (int o = 1; o < 256; o <<= 1) {
    int x = (t >= o) ? tmp[t - o] : 0;
    __syncthreads(); tmp[t] += x; __syncthreads();
  }
  int inclA = tmp[t], totA = tmp[255];
  __syncthreads();
  tmp[t] = b; __syncthreads();
  for (int o = 1; o < 256; o <<= 1) {
    int x = (t >= o) ? tmp[t - o] : 0;
    __syncthreads(); tmp[t] += x; __syncthreads();
  }
  int inclB = tmp[t];
  lex[t] = inclA - a;
  lex[t + 256] = totA + inclB - b;
  __syncthreads();
  const int based = lb << shift;
  const int nd = min(bw, N - based);
  for (int dl = t; dl < nd; dl += 256) {
    int c = lcnt[dl];
    off[based + dl] = e0 - ebase + lex[dl];
    cnt[based + dl] = c;
    inv[based + dl] = 1.0f / fmaxf((float)c, 1.0f);
  }
  __syncthreads();
  lcnt[t] = lex[t]; lcnt[t + 256] = lex[t + 256];
  __syncthreads();
  for (int i = e0 + t; i < e1; i += 256) {
    unsigned u = binned[i];
    int dl = (int)(u >> 17);
    int p = atomicAdd(&lcnt[dl], 1);   // LDS atomic
    csr[e0 - ebase + p] = (int)(u & 0x1FFFFu);
  }
}

// ---------------- merged conversions / weight prep ----------------

// covers both feature arrays in one dispatch
__global__ void cvt2_k(const float* __restrict__ a, unsigned short* __restrict__ oa, int n4a,
                       const float* __restrict__ b, unsigned short* __restrict__ ob, int n4b) {
  int i = blockIdx.x * 256 + threadIdx.x;
  const float* in; unsigned short* out; int idx;
  if (i < n4a) { in = a; out = oa; idx = i; }
  else { idx = i - n4a; if (idx >= n4b) return; in = b; out = ob; }
  float4 v = ((const float4*)in)[idx];
  ushort4 o;
  o.x = pkb(v.x); o.y = pkb(v.y); o.z = pkb(v.z); o.w = pkb(v.w);
  ((ushort4*)out)[idx] = o;
}

// one dispatch: blocks 0-127 Wcat0, 128-255 Wcat1, 256-383 WcatFh(fuse),
// 384-511 WcatFv(fuse,+b1), 512 W2 cvt.
__global__ __launch_bounds__(256) void prep_k(
    const float* __restrict__ Wrel0, const float* __restrict__ Wroot0, unsigned short* __restrict__ Wcat0,
    const float* __restrict__ Wrel1, const float* __restrict__ Wroot1, unsigned short* __restrict__ Wcat1,
    const float* __restrict__ W1,
    const float* __restrict__ Wrel2, const float* __restrict__ Wroot2, const float* __restrict__ brel2,
    unsigned short* __restrict__ WcatFh, float* __restrict__ biasFh,
    const float* __restrict__ Wrel3, const float* __restrict__ Wroot3, const float* __restrict__ brel3,
    const float* __restrict__ b1, unsigned short* __restrict__ WcatFv, float* __restrict__ biasFv,
    const float* __restrict__ W2, unsigned short* __restrict__ W2b) {
  const int blk = blockIdx.x, kk = threadIdx.x;
  if (blk < 256) {            // plain pack: n = blk & 127
    const int n = blk & 127;
    const float* Wrel = (blk < 128) ? Wrel0 : Wrel1;
    const float* Wroot = (blk < 128) ? Wroot0 : Wroot1;
    unsigned short* Wcat = (blk < 128) ? Wcat0 : Wcat1;
    float v = (kk < 128) ? Wrel[(n << 7) + kk] : Wroot[(n << 7) + kk - 128];
    Wcat[n * 256 + kk] = pkb(v);
  } else if (blk < 512) {     // fused W1 @ [Wrel|Wroot]
    const int i = blk & 127;
    const bool fv = (blk >= 384);
    const float* Wrel = fv ? Wrel3 : Wrel2;
    const float* Wroot = fv ? Wroot3 : Wroot2;
    const float* brel = fv ? brel3 : brel2;
    unsigned short* Wf = fv ? WcatFv : WcatFh;
    float* biasF = fv ? biasFv : biasFh;
    const float* __restrict__ Wsrc = (kk < 128) ? Wrel : Wroot;
    const int k = kk & 127;
    float s = 0.f;
    for (int o = 0; o < 128; ++o)
      s += W1[i * 128 + o] * Wsrc[o * 128 + k];
    Wf[i * 256 + kk] = pkb(s);
    if (kk == 0) {
      float sb = fv ? b1[i] : 0.f;
      for (int o = 0; o < 128; ++o) sb += W1[i * 128 + o] * brel[o];
      biasF[i] = sb;
    }
  } else {                    // W2 -> bf16 (4096 elems)
    for (int i = kk; i < 32 * 128; i += 256) W2b[i] = pkb(W2[i]);
  }
}

// ---------------- merged aggregation (both sides), one wave/dst ----------------

__global__ __launch_bounds__(256) void agg2_k(
    const unsigned short* __restrict__ xs0, const int* __restrict__ csr0,
    const int* __restrict__ off0, const int* __restrict__ cnt0,
    const float* __restrict__ inv0, unsigned short* __restrict__ mean0, int n0,
    const unsigned short* __restrict__ xs1, const int* __restrict__ csr1,
    const int* __restrict__ off1, const int* __restrict__ cnt1,
    const float* __restrict__ inv1, unsigned short* __restrict__ mean1, int n1,
    int nblk0) {
  int blk = blockIdx.x;
  const unsigned short* __restrict__ xsrc;
  const int* __restrict__ csr; const int* __restrict__ offp;
  const int* __restrict__ cntp; const float* __restrict__ invp;
  unsigned short* __restrict__ mean; int ndst;
  if (blk < nblk0) {
    xsrc = xs0; csr = csr0; offp = off0; cntp = cnt0; invp = inv0; mean = mean0; ndst = n0;
  } else {
    blk -= nblk0;
    xsrc = xs1; csr = csr1; offp = off1; cntp = cnt1; invp = inv1; mean = mean1; ndst = n1;
  }
  int wid = blk * 4 + (threadIdx.x >> 6);
  int lane = threadIdx.x & 63;
  if (wid >= ndst) return;
  int o = offp[wid], deg = cntp[wid];
  int q = lane >> 4, sl = lane & 15;
  float acc[8] = {0.f, 0.f, 0.f, 0.f, 0.f, 0.f, 0.f, 0.f};
  int sN[4];
#pragma unroll
  for (int j = 0; j < 4; ++j) {
    int e = j * 4 + q;
    sN[j] = (e < deg) ? csr[o + e] : -1;
  }
  for (int i = 0; i < deg; i += 16) {
    int cu[4];
#pragma unroll
    for (int j = 0; j < 4; ++j) {
      cu[j] = sN[j];
      int e = i + 16 + j * 4 + q;
      sN[j] = (e < deg) ? csr[o + e] : -1;
    }
    uint4 v[4];
#pragma unroll
    for (int j = 0; j < 4; ++j)
      if (cu[j] >= 0) v[j] = *(const uint4*)(xsrc + (size_t)cu[j] * 128 + sl * 8);
#pragma unroll
    for (int j = 0; j < 4; ++j) {
      if (cu[j] >= 0) {
        acc[0] += lo16(v[j].x); acc[1] += hi16(v[j].x);
        acc[2] += lo16(v[j].y); acc[3] += hi16(v[j].y);
        acc[4] += lo16(v[j].z); acc[5] += hi16(v[j].z);
        acc[6] += lo16(v[j].w); acc[7] += hi16(v[j].w);
      }
    }
  }
#pragma unroll
  for (int j = 0; j < 8; ++j) {
    acc[j] += __shfl_xor(acc[j], 16);
    acc[j] += __shfl_xor(acc[j], 32);
  }
  if (q == 0) {
    float iv = invp[wid];
    uint4 r;
    r.x = pk2(acc[0] * iv, acc[1] * iv);
    r.y = pk2(acc[2] * iv, acc[3] * iv);
    r.z = pk2(acc[4] * iv, acc[5] * iv);
    r.w = pk2(acc[6] * iv, acc[7] * iv);
    *(uint4*)(mean + (size_t)wid * 128 + sl * 8) = r;
  }
}

// ---------------- merged conv GEMM (both sides), 64 rows/block ----------------

__global__ __launch_bounds__(256) void conv2_k(
    const unsigned short* __restrict__ A1a, const unsigned short* __restrict__ A2a,
    const unsigned short* __restrict__ Wa, const float* __restrict__ ba,
    unsigned short* __restrict__ outa, int na,
    const unsigned short* __restrict__ A1b, const unsigned short* __restrict__ A2b,
    const unsigned short* __restrict__ Wb, const float* __restrict__ bb_,
    unsigned short* __restrict__ outb, int nb, int nblk0, int relu) {
  int blk = blockIdx.x;
  const unsigned short *A1, *A2, *W;
  const float* bias; unsigned short* out; int n;
  if (blk < nblk0) { A1 = A1a; A2 = A2a; W = Wa; bias = ba; out = outa; n = na; }
  else { blk -= nblk0; A1 = A1b; A2 = A2b; W = Wb; bias = bb_; out = outb; n = nb; }

  const int t = threadIdx.x;
  const int l = t & 63, wv = t >> 6;
  const int g = l >> 4;
  const int row0 = blk * 64 + wv * 16;
  int r = row0 + (l & 15); r = r < n ? r : n - 1;

  s16x8 av[8];
#pragma unroll
  for (int c = 0; c < 4; ++c)
    av[c] = *(const s16x8*)(A1 + (size_t)r * 128 + c * 32 + g * 8);
#pragma unroll
  for (int c = 0; c < 4; ++c)
    av[4 + c] = *(const s16x8*)(A2 + (size_t)r * 128 + c * 32 + g * 8);

  f32x4 acc[8] = {};
#pragma unroll
  for (int ch = 0; ch < 8; ++ch) {
#pragma unroll
    for (int fc = 0; fc < 8; ++fc) {
      s16x8 bv = *(const s16x8*)(W + (size_t)(fc * 16 + (l & 15)) * 256 + ch * 32 + g * 8);
      acc[fc] = __builtin_amdgcn_mfma_f32_16x16x32_bf16(av[ch], bv, acc[fc], 0, 0, 0);
    }
  }

#pragma unroll
  for (int fc = 0; fc < 8; ++fc) {
    int col = fc * 16 + (l & 15);
    float bv = bias[col];
    int rbase = row0 + g * 4;
#pragma unroll
    for (int reg = 0; reg < 4; ++reg) {
      int row = rbase + reg;
      if (row < n) {
        float v = acc[fc][reg] + bv;
        if (relu) v = fmaxf(v, 0.f);
        out[(size_t)row * 128 + col] = pkb(v);
      }
    }
  }
}

// ---------------- decoder: h1 = relu(Pv[lv]-Ph[lh]); stage2 MFMA; dot ----------

__global__ __launch_bounds__(256) void dec2_k(
    const unsigned short* __restrict__ Pv, const unsigned short* __restrict__ Ph,
    const int* __restrict__ lv, const int* __restrict__ lh,
    const unsigned short* __restrict__ W2b, const float* __restrict__ b2,
    const float* __restrict__ Wp, const float* __restrict__ bp,
    float* __restrict__ out, int L) {
  const int t = threadIdx.x;
  const int l = t & 63, wv = t >> 6;
  const int g = l >> 4;
  const int row0 = blockIdx.x * 64 + wv * 16;

  int rowc = row0 + (l & 15);
  rowc = rowc < L ? rowc : L - 1;
  const int iv = lv[rowc], ih = lh[rowc];
  const unsigned short* __restrict__ pv = Pv + (size_t)iv * 128 + g * 8;
  const unsigned short* __restrict__ ph = Ph + (size_t)ih * 128 + g * 8;

  uint4 A[4], B[4];
#pragma unroll
  for (int ch = 0; ch < 4; ++ch) A[ch] = *(const uint4*)(pv + ch * 32);
#pragma unroll
  for (int ch = 0; ch < 4; ++ch) B[ch] = *(const uint4*)(ph + ch * 32);

  s16x8 e[4];
#pragma unroll
  for (int ch = 0; ch < 4; ++ch) {
    U4S8 u;
    u.u.x = pk2(fmaxf(lo16(A[ch].x) - lo16(B[ch].x), 0.f), fmaxf(hi16(A[ch].x) - hi16(B[ch].x), 0.f));
    u.u.y = pk2(fmaxf(lo16(A[ch].y) - lo16(B[ch].y), 0.f), fmaxf(hi16(A[ch].y) - hi16(B[ch].y), 0.f));
    u.u.z = pk2(fmaxf(lo16(A[ch].z) - lo16(B[ch].z), 0.f), fmaxf(hi16(A[ch].z) - hi16(B[ch].z), 0.f));
    u.u.w = pk2(fmaxf(lo16(A[ch].w) - lo16(B[ch].w), 0.f), fmaxf(hi16(A[ch].w) - hi16(B[ch].w), 0.f));
    e[ch] = u.s;
  }

  f32x4 acc2[2] = {};
#pragma unroll
  for (int kc = 0; kc < 4; ++kc) {
#pragma unroll
    for (int fc = 0; fc < 2; ++fc) {
      s16x8 bv = *(const s16x8*)(W2b + (size_t)(fc * 16 + (l & 15)) * 128 + kc * 32 + g * 8);
      acc2[fc] = __builtin_amdgcn_mfma_f32_16x16x32_bf16(e[kc], bv, acc2[fc], 0, 0, 0);
    }
  }

  float p[4] = {0.f, 0.f, 0.f, 0.f};
#pragma unroll
  for (int fc = 0; fc < 2; ++fc) {
    int col = fc * 16 + (l & 15);
    float wp = Wp[col], bb = b2[col];
#pragma unroll
    for (int reg = 0; reg < 4; ++reg)
      p[reg] += fmaxf(acc2[fc][reg] + bb, 0.f) * wp;
  }
#pragma unroll
  for (int reg = 0; reg < 4; ++reg) {
    p[reg] += __shfl_xor(p[reg], 1);
    p[reg] += __shfl_xor(p[reg], 2);
    p[reg] += __shfl_xor(p[reg], 4);
    p[reg] += __shfl_xor(p[reg], 8);
  }
  if ((l & 15) == 0) {
    float bb = bp[0];
#pragma unroll
    for (int reg = 0; reg < 4; ++reg) {
      int row = row0 + g * 4 + reg;
      if (row < L) out[row] = p[reg] + bb;
    }
  }
}

// ---------------- host launcher ----------------

extern "C" void kernel_launch(void* const* d_in, const int* in_sizes, int n_in,
                              void* d_out, int out_size, void* d_ws, size_t ws_size,
                              hipStream_t stream) {
  const float* x_virus = (const float*)d_in[0];
  const float* x_host  = (const float*)d_in[1];
  const int* src_vh = (const int*)d_in[2];
  const int* dst_vh = (const int*)d_in[3];
  const int* src_hv = (const int*)d_in[4];
  const int* dst_hv = (const int*)d_in[5];
  const int* lbl_v  = (const int*)d_in[6];
  const int* lbl_h  = (const int*)d_in[7];
  const float* Wrel[4] = {(const float*)d_in[8],  (const float*)d_in[11],
                          (const float*)d_in[14], (const float*)d_in[17]};
  const float* Wroot[4] = {(const float*)d_in[10], (const float*)d_in[13],
                           (const float*)d_in[16], (const float*)d_in[19]};
  const float* bias_c[4] = {(const float*)d_in[9], (const float*)d_in[12],
                            (const float*)d_in[15], (const float*)d_in[18]};
  const float* W1 = (const float*)d_in[20];
  const float* b1 = (const float*)d_in[21];
  const float* W2 = (const float*)d_in[22];
  const float* b2 = (const float*)d_in[23];
  const float* Wp = (const float*)d_in[24];
  const float* bp = (const float*)d_in[25];

  const int NV = in_sizes[0] / D;
  const int NH = in_sizes[1] / D;
  const int E  = in_sizes[2];
  const int L  = in_sizes[6];

  // ---- workspace carve-up ----
  char* ws = (char*)d_ws;
  size_t o = 0;
  auto balloc = [&](size_t nb) { char* p = ws + o; o += (nb + 255) & ~(size_t)255; return p; };
  unsigned short* xvb   = (unsigned short*)balloc((size_t)NV * D * 2);
  unsigned short* xhb   = (unsigned short*)balloc((size_t)NH * D * 2);
  unsigned short* xv1b  = (unsigned short*)balloc((size_t)NV * D * 2);
  unsigned short* Pvb   = (unsigned short*)balloc((size_t)NV * D * 2);
  unsigned short* xh1b  = (unsigned short*)balloc((size_t)NH * D * 2);
  unsigned short* Phb   = (unsigned short*)balloc((size_t)NH * D * 2);
  unsigned short* mean_v = (unsigned short*)balloc((size_t)NV * D * 2);
  unsigned short* mean_h = (unsigned short*)balloc((size_t)NH * D * 2);
  unsigned short* Wcat0 = (unsigned short*)balloc(128 * 256 * 2);
  unsigned short* Wcat1 = (unsigned short*)balloc(128 * 256 * 2);
  unsigned short* WcatFh = (unsigned short*)balloc(128 * 256 * 2);
  unsigned short* WcatFv = (unsigned short*)balloc(128 * 256 * 2);
  unsigned short* W2b = (unsigned short*)balloc(32 * 128 * 2);
  float* biasFh = (float*)balloc(128 * 4);
  float* biasFv = (float*)balloc(128 * 4);
  float* inv_h = (float*)balloc((size_t)NH * 4);
  float* inv_v = (float*)balloc((size_t)NV * 4);
  int* cnt_h = (int*)balloc((size_t)NH * 4);
  int* cnt_v = (int*)balloc((size_t)NV * 4);
  int* off_h = (int*)balloc((size_t)NH * 4);
  int* off_v = (int*)balloc((size_t)NV * 4);
  int* csr_h = (int*)balloc((size_t)E * 4);
  int* csr_v = (int*)balloc((size_t)E * 4);
  int* histmat = (int*)balloc((size_t)512 * PGB * 4);
  int* histoff = (int*)balloc((size_t)512 * PGB * 4);
  unsigned* binned = (unsigned*)balloc((size_t)2 * E * 4);
  int* sums = (int*)balloc(512 * 4);

  auto cdiv = [](int a, int b) { return (a + b - 1) / b; };
  auto calc_shift = [](int n) { int s = 0; while ((1 << s) * 256 < n) ++s; return s; };

  // ---- merged CSR build (all atomics LDS-local) ----
  const int shift0 = calc_shift(NH), shift1 = calc_shift(NV);
  const int nbins0 = cdiv(NH, 1 << shift0), nbins1 = cdiv(NV, 1 << shift1);
  const int nbinsTot = nbins0 + nbins1;
  const int nsc = nbinsTot * PGB;
  part_hist2_k<<<512, 256, 0, stream>>>(dst_vh, dst_hv, histmat, E,
                                        nbins0, nbins1, shift0, shift1);
  scan_chunk_k<<<cdiv(nsc, 1024), 256, 0, stream>>>(histmat, histoff, sums, nsc);
  scan_tops_k<<<1, 256, 0, stream>>>(sums, cdiv(nsc, 1024));
  scan_add_k<<<cdiv(nsc, 256), 256, 0, stream>>>(histoff, sums, nsc);
  part_scatter2_k<<<512, 256, 0, stream>>>(src_vh, dst_vh, src_hv, dst_hv,
                                           histoff, binned, E, nbins0, nbins1,
                                           shift0, shift1);
  csr_bin2_k<<<nbinsTot, 256, 0, stream>>>(binned, histoff,
                                           csr_h, off_h, cnt_h, inv_h,
                                           csr_v, off_v, cnt_v, inv_v,
                                           E, nbins0, nbinsTot, shift0, shift1, NH, NV);

  // ---- conversions + weight prep (2 dispatches) ----
  const int n4v = NV * D / 4, n4h = NH * D / 4;
  cvt2_k<<<cdiv(n4v + n4h, 256), 256, 0, stream>>>(x_virus, xvb, n4v, x_host, xhb, n4h);
  prep_k<<<513, 256, 0, stream>>>(Wrel[0], Wroot[0], Wcat0,
                                  Wrel[1], Wroot[1], Wcat1,
                                  W1,
                                  Wrel[2], Wroot[2], bias_c[2], WcatFh, biasFh,
                                  Wrel[3], Wroot[3], bias_c[3], b1, WcatFv, biasFv,
                                  W2, W2b);

  const int nbh4 = cdiv(NH, 4), nbv4 = cdiv(NV, 4);
  const int nbh64 = cdiv(NH, 64), nbv64 = cdiv(NV, 64);

  // ---- layer 0 (relu): merged agg then merged conv ----
  agg2_k<<<nbh4 + nbv4, 256, 0, stream>>>(
      xvb, csr_h, off_h, cnt_h, inv_h, mean_h, NH,
      xhb, csr_v, off_v, cnt_v, inv_v, mean_v, NV, nbh4);
  conv2_k<<<nbh64 + nbv64, 256, 0, stream>>>(
      mean_h, xhb, Wcat0, bias_c[0], xh1b, NH,
      mean_v, xvb, Wcat1, bias_c[1], xv1b, NV, nbh64, 1);

  // ---- layer 1 fused with W1 (no relu): produces Ph/Pv pre-activations ----
  agg2_k<<<nbh4 + nbv4, 256, 0, stream>>>(
      xv1b, csr_h, off_h, cnt_h, inv_h, mean_h, NH,
      xh1b, csr_v, off_v, cnt_v, inv_v, mean_v, NV, nbh4);
  conv2_k<<<nbh64 + nbv64, 256, 0, stream>>>(
      mean_h, xh1b, WcatFh, biasFh, Phb, NH,
      mean_v, xv1b, WcatFv, biasFv, Pvb, NV, nbh64, 0);

  // ---- decoder ----
  dec2_k<<<cdiv(L, 64), 256, 0, stream>>>(Pvb, Phb, lbl_v, lbl_h, W2b, b2,
                                          Wp, bp, (float*)d_out, L);
}

// Round 15
// 415.630 us; speedup vs baseline: 9.2228x; 1.1061x over previous
//
#include <hip/hip_runtime.h>

// GNN: 2-layer bipartite GraphConv + link decoder.
// Round 15: R14 + conv2 retile to 2 row-frags/wave (128 rows/block) --
// each B-fragment load feeds 2 MFMAs instead of 1. All else identical.

#define D 128
#define PGB 256   // partition blocks per side

typedef float f32x4 __attribute__((ext_vector_type(4)));
typedef short s16x8 __attribute__((ext_vector_type(8)));

__device__ __forceinline__ float lo16(unsigned u) { return __uint_as_float(u << 16); }
__device__ __forceinline__ float hi16(unsigned u) { return __uint_as_float(u & 0xffff0000u); }
__device__ __forceinline__ unsigned short pkb(float f) {
  unsigned b = __float_as_uint(f);
  return (unsigned short)((b + 0x7fffu + ((b >> 16) & 1u)) >> 16);
}
__device__ __forceinline__ unsigned pk2(float a, float b) {
  return (unsigned)pkb(a) | ((unsigned)pkb(b) << 16);
}

union U4S8 { uint4 u; s16x8 s; };

// ---------------- CSR build: merged 2-side counting-sort ----------------

__global__ __launch_bounds__(256) void part_hist2_k(
    const int* __restrict__ dst0, const int* __restrict__ dst1,
    int* __restrict__ histmat, int E, int nbins0, int nbins1,
    int shift0, int shift1) {
  __shared__ int hist[256];
  const int t = threadIdx.x;
  const int side = blockIdx.x >> 8, blk = blockIdx.x & 255;
  const int* __restrict__ dst = side ? dst1 : dst0;
  const int shift = side ? shift1 : shift0;
  const int binbase = side ? nbins0 : 0;
  const int nbins = side ? nbins1 : nbins0;
  hist[t] = 0;
  __syncthreads();
  const int chunk = (E + PGB - 1) / PGB;
  const int e0 = blk * chunk, e1 = min(E, e0 + chunk);
  for (int i = e0 + t; i < e1; i += 256)
    atomicAdd(&hist[dst[i] >> shift], 1);
  __syncthreads();
  if (t < nbins)   // GUARD: each histmat row written by exactly one side
    histmat[(size_t)(binbase + t) * PGB + blk] = hist[t];
}

__global__ void scan_chunk_k(const int* __restrict__ in, int* __restrict__ out,
                             int* __restrict__ sums, int n) {
  __shared__ int lds[256];
  int t = threadIdx.x;
  int base = blockIdx.x * 1024 + t * 4;
  int v0 = (base + 0 < n) ? in[base + 0] : 0;
  int v1 = (base + 1 < n) ? in[base + 1] : 0;
  int v2 = (base + 2 < n) ? in[base + 2] : 0;
  int v3 = (base + 3 < n) ? in[base + 3] : 0;
  int s = v0 + v1 + v2 + v3;
  lds[t] = s;
  __syncthreads();
  for (int off = 1; off < 256; off <<= 1) {
    int x = (t >= off) ? lds[t - off] : 0;
    __syncthreads();
    lds[t] += x;
    __syncthreads();
  }
  int excl = lds[t] - s;
  if (t == 255) sums[blockIdx.x] = lds[255];
  if (base + 0 < n) out[base + 0] = excl; excl += v0;
  if (base + 1 < n) out[base + 1] = excl; excl += v1;
  if (base + 2 < n) out[base + 2] = excl; excl += v2;
  if (base + 3 < n) out[base + 3] = excl;
}

// parallel exclusive scan of the per-chunk totals (nb <= 256)
__global__ void scan_tops_k(int* __restrict__ sums, int nb) {
  __shared__ int lds[256];
  int t = threadIdx.x;
  int v = (t < nb) ? sums[t] : 0;
  lds[t] = v;
  __syncthreads();
  for (int off = 1; off < 256; off <<= 1) {
    int x = (t >= off) ? lds[t - off] : 0;
    __syncthreads();
    lds[t] += x;
    __syncthreads();
  }
  if (t < nb) sums[t] = lds[t] - v;
}

__global__ void scan_add_k(int* __restrict__ out, const int* __restrict__ sums, int n) {
  int i = blockIdx.x * 256 + threadIdx.x;
  if (i < n) out[i] += sums[i >> 10];
}

__global__ __launch_bounds__(256) void part_scatter2_k(
    const int* __restrict__ src0, const int* __restrict__ dst0,
    const int* __restrict__ src1, const int* __restrict__ dst1,
    const int* __restrict__ histoff, unsigned* __restrict__ binned,
    int E, int nbins0, int nbins1, int shift0, int shift1) {
  __shared__ int cur[256];
  const int t = threadIdx.x;
  const int side = blockIdx.x >> 8, blk = blockIdx.x & 255;
  const int* __restrict__ src = side ? src1 : src0;
  const int* __restrict__ dst = side ? dst1 : dst0;
  const int shift = side ? shift1 : shift0;
  const int binbase = side ? nbins0 : 0;
  const int nbins = side ? nbins1 : nbins0;
  if (t < nbins) cur[t] = histoff[(size_t)(binbase + t) * PGB + blk];
  __syncthreads();
  const int chunk = (E + PGB - 1) / PGB;
  const int e0 = blk * chunk, e1 = min(E, e0 + chunk);
  const int mask = (1 << shift) - 1;
  for (int i = e0 + t; i < e1; i += 256) {
    int d = dst[i], s = src[i];
    int b = d >> shift;
    int p = atomicAdd(&cur[b], 1);   // LDS atomic
    binned[p] = ((unsigned)(d & mask) << 17) | (unsigned)s;
  }
}

__global__ __launch_bounds__(256) void csr_bin2_k(
    const unsigned* __restrict__ binned, const int* __restrict__ histoff,
    int* __restrict__ csr0, int* __restrict__ off0, int* __restrict__ cnt0, float* __restrict__ inv0,
    int* __restrict__ csr1, int* __restrict__ off1, int* __restrict__ cnt1, float* __restrict__ inv1,
    int E, int nbins0, int nbinsTot, int shift0, int shift1, int N0, int N1) {
  __shared__ int lcnt[512], lex[512], tmp[256];
  const int t = threadIdx.x, bin = blockIdx.x;
  const int side = (bin >= nbins0);
  const int lb = side ? bin - nbins0 : bin;
  const int shift = side ? shift1 : shift0;
  const int N = side ? N1 : N0;
  const int ebase = side ? E : 0;
  int* __restrict__ csr = side ? csr1 : csr0;
  int* __restrict__ off = side ? off1 : off0;
  int* __restrict__ cnt = side ? cnt1 : cnt0;
  float* __restrict__ inv = side ? inv1 : inv0;
  const int bw = 1 << shift;
  const int e0 = histoff[(size_t)bin * PGB];
  const int e1 = (bin + 1 < nbinsTot) ? histoff[(size_t)(bin + 1) * PGB] : 2 * E;
  lcnt[t] = 0; lcnt[t + 256] = 0;
  __syncthreads();
  for (int i = e0 + t; i < e1; i += 256)
    atomicAdd(&lcnt[binned[i] >> 17], 1);   // LDS atomic
  __syncthreads();
  int a = lcnt[t], b = lcnt[t + 256];
  tmp[t] = a; __syncthreads();
  for (int o = 1; o < 256; o <<= 1) {
    int x = (t >= o) ? tmp[t - o] : 0;
    __syncthreads(); tmp[t] += x; __syncthreads();
  }
  int inclA = tmp[t], totA = tmp[255];
  __syncthreads();
  tmp[t] = b; __syncthreads();
  for (int o = 1; o < 256; o <<= 1) {
    int x = (t >= o) ? tmp[t - o] : 0;
    __syncthreads(); tmp[t] += x; __syncthreads();
  }
  int inclB = tmp[t];
  lex[t] = inclA - a;
  lex[t + 256] = totA + inclB - b;
  __syncthreads();
  const int based = lb << shift;
  const int nd = min(bw, N - based);
  for (int dl = t; dl < nd; dl += 256) {
    int c = lcnt[dl];
    off[based + dl] = e0 - ebase + lex[dl];
    cnt[based + dl] = c;
    inv[based + dl] = 1.0f / fmaxf((float)c, 1.0f);
  }
  __syncthreads();
  lcnt[t] = lex[t]; lcnt[t + 256] = lex[t + 256];
  __syncthreads();
  for (int i = e0 + t; i < e1; i += 256) {
    unsigned u = binned[i];
    int dl = (int)(u >> 17);
    int p = atomicAdd(&lcnt[dl], 1);   // LDS atomic
    csr[e0 - ebase + p] = (int)(u & 0x1FFFFu);
  }
}

// ---------------- merged conversions / weight prep ----------------

__global__ void cvt2_k(const float* __restrict__ a, unsigned short* __restrict__ oa, int n4a,
                       const float* __restrict__ b, unsigned short* __restrict__ ob, int n4b) {
  int i = blockIdx.x * 256 + threadIdx.x;
  const float* in; unsigned short* out; int idx;
  if (i < n4a) { in = a; out = oa; idx = i; }
  else { idx = i - n4a; if (idx >= n4b) return; in = b; out = ob; }
  float4 v = ((const float4*)in)[idx];
  ushort4 o;
  o.x = pkb(v.x); o.y = pkb(v.y); o.z = pkb(v.z); o.w = pkb(v.w);
  ((ushort4*)out)[idx] = o;
}

__global__ __launch_bounds__(256) void prep_k(
    const float* __restrict__ Wrel0, const float* __restrict__ Wroot0, unsigned short* __restrict__ Wcat0,
    const float* __restrict__ Wrel1, const float* __restrict__ Wroot1, unsigned short* __restrict__ Wcat1,
    const float* __restrict__ W1,
    const float* __restrict__ Wrel2, const float* __restrict__ Wroot2, const float* __restrict__ brel2,
    unsigned short* __restrict__ WcatFh, float* __restrict__ biasFh,
    const float* __restrict__ Wrel3, const float* __restrict__ Wroot3, const float* __restrict__ brel3,
    const float* __restrict__ b1, unsigned short* __restrict__ WcatFv, float* __restrict__ biasFv,
    const float* __restrict__ W2, unsigned short* __restrict__ W2b) {
  const int blk = blockIdx.x, kk = threadIdx.x;
  if (blk < 256) {
    const int n = blk & 127;
    const float* Wrel = (blk < 128) ? Wrel0 : Wrel1;
    const float* Wroot = (blk < 128) ? Wroot0 : Wroot1;
    unsigned short* Wcat = (blk < 128) ? Wcat0 : Wcat1;
    float v = (kk < 128) ? Wrel[(n << 7) + kk] : Wroot[(n << 7) + kk - 128];
    Wcat[n * 256 + kk] = pkb(v);
  } else if (blk < 512) {
    const int i = blk & 127;
    const bool fv = (blk >= 384);
    const float* Wrel = fv ? Wrel3 : Wrel2;
    const float* Wroot = fv ? Wroot3 : Wroot2;
    const float* brel = fv ? brel3 : brel2;
    unsigned short* Wf = fv ? WcatFv : WcatFh;
    float* biasF = fv ? biasFv : biasFh;
    const float* __restrict__ Wsrc = (kk < 128) ? Wrel : Wroot;
    const int k = kk & 127;
    float s = 0.f;
    for (int o = 0; o < 128; ++o)
      s += W1[i * 128 + o] * Wsrc[o * 128 + k];
    Wf[i * 256 + kk] = pkb(s);
    if (kk == 0) {
      float sb = fv ? b1[i] : 0.f;
      for (int o = 0; o < 128; ++o) sb += W1[i * 128 + o] * brel[o];
      biasF[i] = sb;
    }
  } else {
    for (int i = kk; i < 32 * 128; i += 256) W2b[i] = pkb(W2[i]);
  }
}

// ---------------- merged aggregation (both sides), one wave/dst ----------------

__global__ __launch_bounds__(256) void agg2_k(
    const unsigned short* __restrict__ xs0, const int* __restrict__ csr0,
    const int* __restrict__ off0, const int* __restrict__ cnt0,
    const float* __restrict__ inv0, unsigned short* __restrict__ mean0, int n0,
    const unsigned short* __restrict__ xs1, const int* __restrict__ csr1,
    const int* __restrict__ off1, const int* __restrict__ cnt1,
    const float* __restrict__ inv1, unsigned short* __restrict__ mean1, int n1,
    int nblk0) {
  int blk = blockIdx.x;
  const unsigned short* __restrict__ xsrc;
  const int* __restrict__ csr; const int* __restrict__ offp;
  const int* __restrict__ cntp; const float* __restrict__ invp;
  unsigned short* __restrict__ mean; int ndst;
  if (blk < nblk0) {
    xsrc = xs0; csr = csr0; offp = off0; cntp = cnt0; invp = inv0; mean = mean0; ndst = n0;
  } else {
    blk -= nblk0;
    xsrc = xs1; csr = csr1; offp = off1; cntp = cnt1; invp = inv1; mean = mean1; ndst = n1;
  }
  int wid = blk * 4 + (threadIdx.x >> 6);
  int lane = threadIdx.x & 63;
  if (wid >= ndst) return;
  int o = offp[wid], deg = cntp[wid];
  int q = lane >> 4, sl = lane & 15;
  float acc[8] = {0.f, 0.f, 0.f, 0.f, 0.f, 0.f, 0.f, 0.f};
  int sN[4];
#pragma unroll
  for (int j = 0; j < 4; ++j) {
    int e = j * 4 + q;
    sN[j] = (e < deg) ? csr[o + e] : -1;
  }
  for (int i = 0; i < deg; i += 16) {
    int cu[4];
#pragma unroll
    for (int j = 0; j < 4; ++j) {
      cu[j] = sN[j];
      int e = i + 16 + j * 4 + q;
      sN[j] = (e < deg) ? csr[o + e] : -1;
    }
    uint4 v[4];
#pragma unroll
    for (int j = 0; j < 4; ++j)
      if (cu[j] >= 0) v[j] = *(const uint4*)(xsrc + (size_t)cu[j] * 128 + sl * 8);
#pragma unroll
    for (int j = 0; j < 4; ++j) {
      if (cu[j] >= 0) {
        acc[0] += lo16(v[j].x); acc[1] += hi16(v[j].x);
        acc[2] += lo16(v[j].y); acc[3] += hi16(v[j].y);
        acc[4] += lo16(v[j].z); acc[5] += hi16(v[j].z);
        acc[6] += lo16(v[j].w); acc[7] += hi16(v[j].w);
      }
    }
  }
#pragma unroll
  for (int j = 0; j < 8; ++j) {
    acc[j] += __shfl_xor(acc[j], 16);
    acc[j] += __shfl_xor(acc[j], 32);
  }
  if (q == 0) {
    float iv = invp[wid];
    uint4 r;
    r.x = pk2(acc[0] * iv, acc[1] * iv);
    r.y = pk2(acc[2] * iv, acc[3] * iv);
    r.z = pk2(acc[4] * iv, acc[5] * iv);
    r.w = pk2(acc[6] * iv, acc[7] * iv);
    *(uint4*)(mean + (size_t)wid * 128 + sl * 8) = r;
  }
}

// ---------------- merged conv GEMM (both sides), 128 rows/block ----------------
// Wave w owns rows blk*128 + w*32 .. +32 (2 row-frags); each B-frag load
// feeds 2 MFMAs. out = [A1|A2] @ W^T + bias.

__global__ __launch_bounds__(256) void conv2_k(
    const unsigned short* __restrict__ A1a, const unsigned short* __restrict__ A2a,
    const unsigned short* __restrict__ Wa, const float* __restrict__ ba,
    unsigned short* __restrict__ outa, int na,
    const unsigned short* __restrict__ A1b, const unsigned short* __restrict__ A2b,
    const unsigned short* __restrict__ Wb, const float* __restrict__ bb_,
    unsigned short* __restrict__ outb, int nb, int nblk0, int relu) {
  int blk = blockIdx.x;
  const unsigned short *A1, *A2, *W;
  const float* bias; unsigned short* out; int n;
  if (blk < nblk0) { A1 = A1a; A2 = A2a; W = Wa; bias = ba; out = outa; n = na; }
  else { blk -= nblk0; A1 = A1b; A2 = A2b; W = Wb; bias = bb_; out = outb; n = nb; }

  const int t = threadIdx.x;
  const int l = t & 63, wv = t >> 6;
  const int g = l >> 4;
  const int row0 = blk * 128 + wv * 32;
  int r0 = row0 + (l & 15);      r0 = r0 < n ? r0 : n - 1;
  int r1 = row0 + 16 + (l & 15); r1 = r1 < n ? r1 : n - 1;

  s16x8 av[2][8];
#pragma unroll
  for (int c = 0; c < 4; ++c) {
    av[0][c]     = *(const s16x8*)(A1 + (size_t)r0 * 128 + c * 32 + g * 8);
    av[1][c]     = *(const s16x8*)(A1 + (size_t)r1 * 128 + c * 32 + g * 8);
    av[0][4 + c] = *(const s16x8*)(A2 + (size_t)r0 * 128 + c * 32 + g * 8);
    av[1][4 + c] = *(const s16x8*)(A2 + (size_t)r1 * 128 + c * 32 + g * 8);
  }

  f32x4 acc[2][8] = {};
#pragma unroll
  for (int ch = 0; ch < 8; ++ch) {
#pragma unroll
    for (int fc = 0; fc < 8; ++fc) {
      s16x8 bv = *(const s16x8*)(W + (size_t)(fc * 16 + (l & 15)) * 256 + ch * 32 + g * 8);
      acc[0][fc] = __builtin_amdgcn_mfma_f32_16x16x32_bf16(av[0][ch], bv, acc[0][fc], 0, 0, 0);
      acc[1][fc] = __builtin_amdgcn_mfma_f32_16x16x32_bf16(av[1][ch], bv, acc[1][fc], 0, 0, 0);
    }
  }

#pragma unroll
  for (int fc = 0; fc < 8; ++fc) {
    int col = fc * 16 + (l & 15);
    float bv = bias[col];
#pragma unroll
    for (int fr = 0; fr < 2; ++fr) {
      int rbase = row0 + fr * 16 + g * 4;
#pragma unroll
      for (int reg = 0; reg < 4; ++reg) {
        int row = rbase + reg;
        if (row < n) {
          float v = acc[fr][fc][reg] + bv;
          if (relu) v = fmaxf(v, 0.f);
          out[(size_t)row * 128 + col] = pkb(v);
        }
      }
    }
  }
}

// ---------------- decoder: h1 = relu(Pv[lv]-Ph[lh]); stage2 MFMA; dot ----------

__global__ __launch_bounds__(256) void dec2_k(
    const unsigned short* __restrict__ Pv, const unsigned short* __restrict__ Ph,
    const int* __restrict__ lv, const int* __restrict__ lh,
    const unsigned short* __restrict__ W2b, const float* __restrict__ b2,
    const float* __restrict__ Wp, const float* __restrict__ bp,
    float* __restrict__ out, int L) {
  const int t = threadIdx.x;
  const int l = t & 63, wv = t >> 6;
  const int g = l >> 4;
  const int row0 = blockIdx.x * 64 + wv * 16;

  int rowc = row0 + (l & 15);
  rowc = rowc < L ? rowc : L - 1;
  const int iv = lv[rowc], ih = lh[rowc];
  const unsigned short* __restrict__ pv = Pv + (size_t)iv * 128 + g * 8;
  const unsigned short* __restrict__ ph = Ph + (size_t)ih * 128 + g * 8;

  uint4 A[4], B[4];
#pragma unroll
  for (int ch = 0; ch < 4; ++ch) A[ch] = *(const uint4*)(pv + ch * 32);
#pragma unroll
  for (int ch = 0; ch < 4; ++ch) B[ch] = *(const uint4*)(ph + ch * 32);

  s16x8 e[4];
#pragma unroll
  for (int ch = 0; ch < 4; ++ch) {
    U4S8 u;
    u.u.x = pk2(fmaxf(lo16(A[ch].x) - lo16(B[ch].x), 0.f), fmaxf(hi16(A[ch].x) - hi16(B[ch].x), 0.f));
    u.u.y = pk2(fmaxf(lo16(A[ch].y) - lo16(B[ch].y), 0.f), fmaxf(hi16(A[ch].y) - hi16(B[ch].y), 0.f));
    u.u.z = pk2(fmaxf(lo16(A[ch].z) - lo16(B[ch].z), 0.f), fmaxf(hi16(A[ch].z) - hi16(B[ch].z), 0.f));
    u.u.w = pk2(fmaxf(lo16(A[ch].w) - lo16(B[ch].w), 0.f), fmaxf(hi16(A[ch].w) - hi16(B[ch].w), 0.f));
    e[ch] = u.s;
  }

  f32x4 acc2[2] = {};
#pragma unroll
  for (int kc = 0; kc < 4; ++kc) {
#pragma unroll
    for (int fc = 0; fc < 2; ++fc) {
      s16x8 bv = *(const s16x8*)(W2b + (size_t)(fc * 16 + (l & 15)) * 128 + kc * 32 + g * 8);
      acc2[fc] = __builtin_amdgcn_mfma_f32_16x16x32_bf16(e[kc], bv, acc2[fc], 0, 0, 0);
    }
  }

  float p[4] = {0.f, 0.f, 0.f, 0.f};
#pragma unroll
  for (int fc = 0; fc < 2; ++fc) {
    int col = fc * 16 + (l & 15);
    float wp = Wp[col], bb = b2[col];
#pragma unroll
    for (int reg = 0; reg < 4; ++reg)
      p[reg] += fmaxf(acc2[fc][reg] + bb, 0.f) * wp;
  }
#pragma unroll
  for (int reg = 0; reg < 4; ++reg) {
    p[reg] += __shfl_xor(p[reg], 1);
    p[reg] += __shfl_xor(p[reg], 2);
    p[reg] += __shfl_xor(p[reg], 4);
    p[reg] += __shfl_xor(p[reg], 8);
  }
  if ((l & 15) == 0) {
    float bb = bp[0];
#pragma unroll
    for (int reg = 0; reg < 4; ++reg) {
      int row = row0 + g * 4 + reg;
      if (row < L) out[row] = p[reg] + bb;
    }
  }
}

// ---------------- host launcher ----------------

extern "C" void kernel_launch(void* const* d_in, const int* in_sizes, int n_in,
                              void* d_out, int out_size, void* d_ws, size_t ws_size,
                              hipStream_t stream) {
  const float* x_virus = (const float*)d_in[0];
  const float* x_host  = (const float*)d_in[1];
  const int* src_vh = (const int*)d_in[2];
  const int* dst_vh = (const int*)d_in[3];
  const int* src_hv = (const int*)d_in[4];
  const int* dst_hv = (const int*)d_in[5];
  const int* lbl_v  = (const int*)d_in[6];
  const int* lbl_h  = (const int*)d_in[7];
  const float* Wrel[4] = {(const float*)d_in[8],  (const float*)d_in[11],
                          (const float*)d_in[14], (const float*)d_in[17]};
  const float* Wroot[4] = {(const float*)d_in[10], (const float*)d_in[13],
                           (const float*)d_in[16], (const float*)d_in[19]};
  const float* bias_c[4] = {(const float*)d_in[9], (const float*)d_in[12],
                            (const float*)d_in[15], (const float*)d_in[18]};
  const float* W1 = (const float*)d_in[20];
  const float* b1 = (const float*)d_in[21];
  const float* W2 = (const float*)d_in[22];
  const float* b2 = (const float*)d_in[23];
  const float* Wp = (const float*)d_in[24];
  const float* bp = (const float*)d_in[25];

  const int NV = in_sizes[0] / D;
  const int NH = in_sizes[1] / D;
  const int E  = in_sizes[2];
  const int L  = in_sizes[6];

  // ---- workspace carve-up ----
  char* ws = (char*)d_ws;
  size_t o = 0;
  auto balloc = [&](size_t nb) { char* p = ws + o; o += (nb + 255) & ~(size_t)255; return p; };
  unsigned short* xvb   = (unsigned short*)balloc((size_t)NV * D * 2);
  unsigned short* xhb   = (unsigned short*)balloc((size_t)NH * D * 2);
  unsigned short* xv1b  = (unsigned short*)balloc((size_t)NV * D * 2);
  unsigned short* Pvb   = (unsigned short*)balloc((size_t)NV * D * 2);
  unsigned short* xh1b  = (unsigned short*)balloc((size_t)NH * D * 2);
  unsigned short* Phb   = (unsigned short*)balloc((size_t)NH * D * 2);
  unsigned short* mean_v = (unsigned short*)balloc((size_t)NV * D * 2);
  unsigned short* mean_h = (unsigned short*)balloc((size_t)NH * D * 2);
  unsigned short* Wcat0 = (unsigned short*)balloc(128 * 256 * 2);
  unsigned short* Wcat1 = (unsigned short*)balloc(128 * 256 * 2);
  unsigned short* WcatFh = (unsigned short*)balloc(128 * 256 * 2);
  unsigned short* WcatFv = (unsigned short*)balloc(128 * 256 * 2);
  unsigned short* W2b = (unsigned short*)balloc(32 * 128 * 2);
  float* biasFh = (float*)balloc(128 * 4);
  float* biasFv = (float*)balloc(128 * 4);
  float* inv_h = (float*)balloc((size_t)NH * 4);
  float* inv_v = (float*)balloc((size_t)NV * 4);
  int* cnt_h = (int*)balloc((size_t)NH * 4);
  int* cnt_v = (int*)balloc((size_t)NV * 4);
  int* off_h = (int*)balloc((size_t)NH * 4);
  int* off_v = (int*)balloc((size_t)NV * 4);
  int* csr_h = (int*)balloc((size_t)E * 4);
  int* csr_v = (int*)balloc((size_t)E * 4);
  int* histmat = (int*)balloc((size_t)512 * PGB * 4);
  int* histoff = (int*)balloc((size_t)512 * PGB * 4);
  unsigned* binned = (unsigned*)balloc((size_t)2 * E * 4);
  int* sums = (int*)balloc(512 * 4);

  auto cdiv = [](int a, int b) { return (a + b - 1) / b; };
  auto calc_shift = [](int n) { int s = 0; while ((1 << s) * 256 < n) ++s; return s; };

  // ---- merged CSR build (all atomics LDS-local) ----
  const int shift0 = calc_shift(NH), shift1 = calc_shift(NV);
  const int nbins0 = cdiv(NH, 1 << shift0), nbins1 = cdiv(NV, 1 << shift1);
  const int nbinsTot = nbins0 + nbins1;
  const int nsc = nbinsTot * PGB;
  part_hist2_k<<<512, 256, 0, stream>>>(dst_vh, dst_hv, histmat, E,
                                        nbins0, nbins1, shift0, shift1);
  scan_chunk_k<<<cdiv(nsc, 1024), 256, 0, stream>>>(histmat, histoff, sums, nsc);
  scan_tops_k<<<1, 256, 0, stream>>>(sums, cdiv(nsc, 1024));
  scan_add_k<<<cdiv(nsc, 256), 256, 0, stream>>>(histoff, sums, nsc);
  part_scatter2_k<<<512, 256, 0, stream>>>(src_vh, dst_vh, src_hv, dst_hv,
                                           histoff, binned, E, nbins0, nbins1,
                                           shift0, shift1);
  csr_bin2_k<<<nbinsTot, 256, 0, stream>>>(binned, histoff,
                                           csr_h, off_h, cnt_h, inv_h,
                                           csr_v, off_v, cnt_v, inv_v,
                                           E, nbins0, nbinsTot, shift0, shift1, NH, NV);

  // ---- conversions + weight prep (2 dispatches) ----
  const int n4v = NV * D / 4, n4h = NH * D / 4;
  cvt2_k<<<cdiv(n4v + n4h, 256), 256, 0, stream>>>(x_virus, xvb, n4v, x_host, xhb, n4h);
  prep_k<<<513, 256, 0, stream>>>(Wrel[0], Wroot[0], Wcat0,
                                  Wrel[1], Wroot[1], Wcat1,
                                  W1,
                                  Wrel[2], Wroot[2], bias_c[2], WcatFh, biasFh,
                                  Wrel[3], Wroot[3], bias_c[3], b1, WcatFv, biasFv,
                                  W2, W2b);

  const int nbh4 = cdiv(NH, 4), nbv4 = cdiv(NV, 4);
  const int nbh128 = cdiv(NH, 128), nbv128 = cdiv(NV, 128);

  // ---- layer 0 (relu): merged agg then merged conv ----
  agg2_k<<<nbh4 + nbv4, 256, 0, stream>>>(
      xvb, csr_h, off_h, cnt_h, inv_h, mean_h, NH,
      xhb, csr_v, off_v, cnt_v, inv_v, mean_v, NV, nbh4);
  conv2_k<<<nbh128 + nbv128, 256, 0, stream>>>(
      mean_h, xhb, Wcat0, bias_c[0], xh1b, NH,
      mean_v, xvb, Wcat1, bias_c[1], xv1b, NV, nbh128, 1);

  // ---- layer 1 fused with W1 (no relu): produces Ph/Pv pre-activations ----
  agg2_k<<<nbh4 + nbv4, 256, 0, stream>>>(
      xv1b, csr_h, off_h, cnt_h, inv_h, mean_h, NH,
      xh1b, csr_v, off_v, cnt_v, inv_v, mean_v, NV, nbh4);
  conv2_k<<<nbh128 + nbv128, 256, 0, stream>>>(
      mean_h, xh1b, WcatFh, biasFh, Phb, NH,
      mean_v, xv1b, WcatFv, biasFv, Pvb, NV, nbh128, 0);

  // ---- decoder ----
  dec2_k<<<cdiv(L, 64), 256, 0, stream>>>(Pvb, Phb, lbl_v, lbl_h, W2b, b2,
                                          Wp, bp, (float*)d_out, L);
}

// Round 16
// 404.895 us; speedup vs baseline: 9.4673x; 1.0265x over previous
//
#include <hip/hip_runtime.h>

// GNN: 2-layer bipartite GraphConv + link decoder.
// Round 16: R15 + dispatch consolidation: cvt/prep fused into hist dispatch,
// scan_tops folded into scan_add (per-block local tops scan). 13->10 dispatches.

#define D 128
#define PGB 256   // partition blocks per side

typedef float f32x4 __attribute__((ext_vector_type(4)));
typedef short s16x8 __attribute__((ext_vector_type(8)));

__device__ __forceinline__ float lo16(unsigned u) { return __uint_as_float(u << 16); }
__device__ __forceinline__ float hi16(unsigned u) { return __uint_as_float(u & 0xffff0000u); }
__device__ __forceinline__ unsigned short pkb(float f) {
  unsigned b = __float_as_uint(f);
  return (unsigned short)((b + 0x7fffu + ((b >> 16) & 1u)) >> 16);
}
__device__ __forceinline__ unsigned pk2(float a, float b) {
  return (unsigned)pkb(a) | ((unsigned)pkb(b) << 16);
}

union U4S8 { uint4 u; s16x8 s; };

// ---------------- fused: histograms (both sides) + feature cvt + weight prep ----
// blocks [0,512): per-side per-chunk histograms
// blocks [512, 512+ncvt): f32->bf16 feature conversion
// blocks [512+ncvt, 512+ncvt+513): weight packs / W1-fused weights / W2 cvt

__global__ __launch_bounds__(256) void hist_cvt_prep_k(
    const int* __restrict__ dst0, const int* __restrict__ dst1,
    int* __restrict__ histmat, int E, int nbins0, int nbins1,
    int shift0, int shift1,
    const float* __restrict__ xa, unsigned short* __restrict__ oxa, int n4a,
    const float* __restrict__ xb, unsigned short* __restrict__ oxb, int n4b,
    int ncvt,
    const float* __restrict__ Wrel0, const float* __restrict__ Wroot0, unsigned short* __restrict__ Wcat0,
    const float* __restrict__ Wrel1, const float* __restrict__ Wroot1, unsigned short* __restrict__ Wcat1,
    const float* __restrict__ W1,
    const float* __restrict__ Wrel2, const float* __restrict__ Wroot2, const float* __restrict__ brel2,
    unsigned short* __restrict__ WcatFh, float* __restrict__ biasFh,
    const float* __restrict__ Wrel3, const float* __restrict__ Wroot3, const float* __restrict__ brel3,
    const float* __restrict__ b1, unsigned short* __restrict__ WcatFv, float* __restrict__ biasFv,
    const float* __restrict__ W2, unsigned short* __restrict__ W2b) {
  const int gblk = blockIdx.x;
  const int kk = threadIdx.x;

  if (gblk < 512) {
    // ---- histogram ----
    __shared__ int hist[256];
    const int side = gblk >> 8, blk = gblk & 255;
    const int* __restrict__ dst = side ? dst1 : dst0;
    const int shift = side ? shift1 : shift0;
    const int binbase = side ? nbins0 : 0;
    const int nbins = side ? nbins1 : nbins0;
    hist[kk] = 0;
    __syncthreads();
    const int chunk = (E + PGB - 1) / PGB;
    const int e0 = blk * chunk, e1 = min(E, e0 + chunk);
    for (int i = e0 + kk; i < e1; i += 256)
      atomicAdd(&hist[dst[i] >> shift], 1);
    __syncthreads();
    if (kk < nbins)   // GUARD: each histmat row written by exactly one side
      histmat[(size_t)(binbase + kk) * PGB + blk] = hist[kk];
    return;
  }
  if (gblk < 512 + ncvt) {
    // ---- feature conversion ----
    int i = (gblk - 512) * 256 + kk;
    const float* in; unsigned short* out; int idx;
    if (i < n4a) { in = xa; out = oxa; idx = i; }
    else { idx = i - n4a; if (idx >= n4b) return; in = xb; out = oxb; }
    float4 v = ((const float4*)in)[idx];
    ushort4 o;
    o.x = pkb(v.x); o.y = pkb(v.y); o.z = pkb(v.z); o.w = pkb(v.w);
    ((ushort4*)out)[idx] = o;
    return;
  }
  // ---- weight prep ----
  const int blk = gblk - 512 - ncvt;    // 0..512
  if (blk < 256) {
    const int n = blk & 127;
    const float* Wrel = (blk < 128) ? Wrel0 : Wrel1;
    const float* Wroot = (blk < 128) ? Wroot0 : Wroot1;
    unsigned short* Wcat = (blk < 128) ? Wcat0 : Wcat1;
    float v = (kk < 128) ? Wrel[(n << 7) + kk] : Wroot[(n << 7) + kk - 128];
    Wcat[n * 256 + kk] = pkb(v);
  } else if (blk < 512) {
    const int i = blk & 127;
    const bool fv = (blk >= 384);
    const float* Wrel = fv ? Wrel3 : Wrel2;
    const float* Wroot = fv ? Wroot3 : Wroot2;
    const float* brel = fv ? brel3 : brel2;
    unsigned short* Wf = fv ? WcatFv : WcatFh;
    float* biasF = fv ? biasFv : biasFh;
    const float* __restrict__ Wsrc = (kk < 128) ? Wrel : Wroot;
    const int k = kk & 127;
    float s = 0.f;
    for (int o = 0; o < 128; ++o)
      s += W1[i * 128 + o] * Wsrc[o * 128 + k];
    Wf[i * 256 + kk] = pkb(s);
    if (kk == 0) {
      float sb = fv ? b1[i] : 0.f;
      for (int o = 0; o < 128; ++o) sb += W1[i * 128 + o] * brel[o];
      biasF[i] = sb;
    }
  } else {
    for (int i = kk; i < 32 * 128; i += 256) W2b[i] = pkb(W2[i]);
  }
}

__global__ void scan_chunk_k(const int* __restrict__ in, int* __restrict__ out,
                             int* __restrict__ sums, int n) {
  __shared__ int lds[256];
  int t = threadIdx.x;
  int base = blockIdx.x * 1024 + t * 4;
  int v0 = (base + 0 < n) ? in[base + 0] : 0;
  int v1 = (base + 1 < n) ? in[base + 1] : 0;
  int v2 = (base + 2 < n) ? in[base + 2] : 0;
  int v3 = (base + 3 < n) ? in[base + 3] : 0;
  int s = v0 + v1 + v2 + v3;
  lds[t] = s;
  __syncthreads();
  for (int off = 1; off < 256; off <<= 1) {
    int x = (t >= off) ? lds[t - off] : 0;
    __syncthreads();
    lds[t] += x;
    __syncthreads();
  }
  int excl = lds[t] - s;
  if (t == 255) sums[blockIdx.x] = lds[255];
  if (base + 0 < n) out[base + 0] = excl; excl += v0;
  if (base + 1 < n) out[base + 1] = excl; excl += v1;
  if (base + 2 < n) out[base + 2] = excl; excl += v2;
  if (base + 3 < n) out[base + 3] = excl;
}

// scan_add with per-block local tops scan (nb <= 256): removes scan_tops pass.
__global__ void scan_add2_k(int* __restrict__ out, const int* __restrict__ sums,
                            int n, int nb) {
  __shared__ int lds[256];
  int t = threadIdx.x;
  int v = (t < nb) ? sums[t] : 0;
  lds[t] = v;
  __syncthreads();
  for (int off = 1; off < 256; off <<= 1) {
    int x = (t >= off) ? lds[t - off] : 0;
    __syncthreads();
    lds[t] += x;
    __syncthreads();
  }
  __shared__ int excl[256];
  excl[t] = lds[t] - v;
  __syncthreads();
  int i = blockIdx.x * 256 + t;
  if (i < n) out[i] += excl[i >> 10];
}

__global__ __launch_bounds__(256) void part_scatter2_k(
    const int* __restrict__ src0, const int* __restrict__ dst0,
    const int* __restrict__ src1, const int* __restrict__ dst1,
    const int* __restrict__ histoff, unsigned* __restrict__ binned,
    int E, int nbins0, int nbins1, int shift0, int shift1) {
  __shared__ int cur[256];
  const int t = threadIdx.x;
  const int side = blockIdx.x >> 8, blk = blockIdx.x & 255;
  const int* __restrict__ src = side ? src1 : src0;
  const int* __restrict__ dst = side ? dst1 : dst0;
  const int shift = side ? shift1 : shift0;
  const int binbase = side ? nbins0 : 0;
  const int nbins = side ? nbins1 : nbins0;
  if (t < nbins) cur[t] = histoff[(size_t)(binbase + t) * PGB + blk];
  __syncthreads();
  const int chunk = (E + PGB - 1) / PGB;
  const int e0 = blk * chunk, e1 = min(E, e0 + chunk);
  const int mask = (1 << shift) - 1;
  for (int i = e0 + t; i < e1; i += 256) {
    int d = dst[i], s = src[i];
    int b = d >> shift;
    int p = atomicAdd(&cur[b], 1);   // LDS atomic
    binned[p] = ((unsigned)(d & mask) << 17) | (unsigned)s;
  }
}

__global__ __launch_bounds__(256) void csr_bin2_k(
    const unsigned* __restrict__ binned, const int* __restrict__ histoff,
    int* __restrict__ csr0, int* __restrict__ off0, int* __restrict__ cnt0, float* __restrict__ inv0,
    int* __restrict__ csr1, int* __restrict__ off1, int* __restrict__ cnt1, float* __restrict__ inv1,
    int E, int nbins0, int nbinsTot, int shift0, int shift1, int N0, int N1) {
  __shared__ int lcnt[512], lex[512], tmp[256];
  const int t = threadIdx.x, bin = blockIdx.x;
  const int side = (bin >= nbins0);
  const int lb = side ? bin - nbins0 : bin;
  const int shift = side ? shift1 : shift0;
  const int N = side ? N1 : N0;
  const int ebase = side ? E : 0;
  int* __restrict__ csr = side ? csr1 : csr0;
  int* __restrict__ off = side ? off1 : off0;
  int* __restrict__ cnt = side ? cnt1 : cnt0;
  float* __restrict__ inv = side ? inv1 : inv0;
  const int bw = 1 << shift;
  const int e0 = histoff[(size_t)bin * PGB];
  const int e1 = (bin + 1 < nbinsTot) ? histoff[(size_t)(bin + 1) * PGB] : 2 * E;
  lcnt[t] = 0; lcnt[t + 256] = 0;
  __syncthreads();
  for (int i = e0 + t; i < e1; i += 256)
    atomicAdd(&lcnt[binned[i] >> 17], 1);   // LDS atomic
  __syncthreads();
  int a = lcnt[t], b = lcnt[t + 256];
  tmp[t] = a; __syncthreads();
  for (int o = 1; o < 256; o <<= 1) {
    int x = (t >= o) ? tmp[t - o] : 0;
    __syncthreads(); tmp[t] += x; __syncthreads();
  }
  int inclA = tmp[t], totA = tmp[255];
  __syncthreads();
  tmp[t] = b; __syncthreads();
  for (int o = 1; o < 256; o <<= 1) {
    int x = (t >= o) ? tmp[t - o] : 0;
    __syncthreads(); tmp[t] += x; __syncthreads();
  }
  int inclB = tmp[t];
  lex[t] = inclA - a;
  lex[t + 256] = totA + inclB - b;
  __syncthreads();
  const int based = lb << shift;
  const int nd = min(bw, N - based);
  for (int dl = t; dl < nd; dl += 256) {
    int c = lcnt[dl];
    off[based + dl] = e0 - ebase + lex[dl];
    cnt[based + dl] = c;
    inv[based + dl] = 1.0f / fmaxf((float)c, 1.0f);
  }
  __syncthreads();
  lcnt[t] = lex[t]; lcnt[t + 256] = lex[t + 256];
  __syncthreads();
  for (int i = e0 + t; i < e1; i += 256) {
    unsigned u = binned[i];
    int dl = (int)(u >> 17);
    int p = atomicAdd(&lcnt[dl], 1);   // LDS atomic
    csr[e0 - ebase + p] = (int)(u & 0x1FFFFu);
  }
}

// ---------------- merged aggregation (both sides), one wave/dst ----------------

__global__ __launch_bounds__(256) void agg2_k(
    const unsigned short* __restrict__ xs0, const int* __restrict__ csr0,
    const int* __restrict__ off0, const int* __restrict__ cnt0,
    const float* __restrict__ inv0, unsigned short* __restrict__ mean0, int n0,
    const unsigned short* __restrict__ xs1, const int* __restrict__ csr1,
    const int* __restrict__ off1, const int* __restrict__ cnt1,
    const float* __restrict__ inv1, unsigned short* __restrict__ mean1, int n1,
    int nblk0) {
  int blk = blockIdx.x;
  const unsigned short* __restrict__ xsrc;
  const int* __restrict__ csr; const int* __restrict__ offp;
  const int* __restrict__ cntp; const float* __restrict__ invp;
  unsigned short* __restrict__ mean; int ndst;
  if (blk < nblk0) {
    xsrc = xs0; csr = csr0; offp = off0; cntp = cnt0; invp = inv0; mean = mean0; ndst = n0;
  } else {
    blk -= nblk0;
    xsrc = xs1; csr = csr1; offp = off1; cntp = cnt1; invp = inv1; mean = mean1; ndst = n1;
  }
  int wid = blk * 4 + (threadIdx.x >> 6);
  int lane = threadIdx.x & 63;
  if (wid >= ndst) return;
  int o = offp[wid], deg = cntp[wid];
  int q = lane >> 4, sl = lane & 15;
  float acc[8] = {0.f, 0.f, 0.f, 0.f, 0.f, 0.f, 0.f, 0.f};
  int sN[4];
#pragma unroll
  for (int j = 0; j < 4; ++j) {
    int e = j * 4 + q;
    sN[j] = (e < deg) ? csr[o + e] : -1;
  }
  for (int i = 0; i < deg; i += 16) {
    int cu[4];
#pragma unroll
    for (int j = 0; j < 4; ++j) {
      cu[j] = sN[j];
      int e = i + 16 + j * 4 + q;
      sN[j] = (e < deg) ? csr[o + e] : -1;
    }
    uint4 v[4];
#pragma unroll
    for (int j = 0; j < 4; ++j)
      if (cu[j] >= 0) v[j] = *(const uint4*)(xsrc + (size_t)cu[j] * 128 + sl * 8);
#pragma unroll
    for (int j = 0; j < 4; ++j) {
      if (cu[j] >= 0) {
        acc[0] += lo16(v[j].x); acc[1] += hi16(v[j].x);
        acc[2] += lo16(v[j].y); acc[3] += hi16(v[j].y);
        acc[4] += lo16(v[j].z); acc[5] += hi16(v[j].z);
        acc[6] += lo16(v[j].w); acc[7] += hi16(v[j].w);
      }
    }
  }
#pragma unroll
  for (int j = 0; j < 8; ++j) {
    acc[j] += __shfl_xor(acc[j], 16);
    acc[j] += __shfl_xor(acc[j], 32);
  }
  if (q == 0) {
    float iv = invp[wid];
    uint4 r;
    r.x = pk2(acc[0] * iv, acc[1] * iv);
    r.y = pk2(acc[2] * iv, acc[3] * iv);
    r.z = pk2(acc[4] * iv, acc[5] * iv);
    r.w = pk2(acc[6] * iv, acc[7] * iv);
    *(uint4*)(mean + (size_t)wid * 128 + sl * 8) = r;
  }
}

// ---------------- merged conv GEMM (both sides), 128 rows/block ----------------

__global__ __launch_bounds__(256) void conv2_k(
    const unsigned short* __restrict__ A1a, const unsigned short* __restrict__ A2a,
    const unsigned short* __restrict__ Wa, const float* __restrict__ ba,
    unsigned short* __restrict__ outa, int na,
    const unsigned short* __restrict__ A1b, const unsigned short* __restrict__ A2b,
    const unsigned short* __restrict__ Wb, const float* __restrict__ bb_,
    unsigned short* __restrict__ outb, int nb, int nblk0, int relu) {
  int blk = blockIdx.x;
  const unsigned short *A1, *A2, *W;
  const float* bias; unsigned short* out; int n;
  if (blk < nblk0) { A1 = A1a; A2 = A2a; W = Wa; bias = ba; out = outa; n = na; }
  else { blk -= nblk0; A1 = A1b; A2 = A2b; W = Wb; bias = bb_; out = outb; n = nb; }

  const int t = threadIdx.x;
  const int l = t & 63, wv = t >> 6;
  const int g = l >> 4;
  const int row0 = blk * 128 + wv * 32;
  int r0 = row0 + (l & 15);      r0 = r0 < n ? r0 : n - 1;
  int r1 = row0 + 16 + (l & 15); r1 = r1 < n ? r1 : n - 1;

  s16x8 av[2][8];
#pragma unroll
  for (int c = 0; c < 4; ++c) {
    av[0][c]     = *(const s16x8*)(A1 + (size_t)r0 * 128 + c * 32 + g * 8);
    av[1][c]     = *(const s16x8*)(A1 + (size_t)r1 * 128 + c * 32 + g * 8);
    av[0][4 + c] = *(const s16x8*)(A2 + (size_t)r0 * 128 + c * 32 + g * 8);
    av[1][4 + c] = *(const s16x8*)(A2 + (size_t)r1 * 128 + c * 32 + g * 8);
  }

  f32x4 acc[2][8] = {};
#pragma unroll
  for (int ch = 0; ch < 8; ++ch) {
#pragma unroll
    for (int fc = 0; fc < 8; ++fc) {
      s16x8 bv = *(const s16x8*)(W + (size_t)(fc * 16 + (l & 15)) * 256 + ch * 32 + g * 8);
      acc[0][fc] = __builtin_amdgcn_mfma_f32_16x16x32_bf16(av[0][ch], bv, acc[0][fc], 0, 0, 0);
      acc[1][fc] = __builtin_amdgcn_mfma_f32_16x16x32_bf16(av[1][ch], bv, acc[1][fc], 0, 0, 0);
    }
  }

#pragma unroll
  for (int fc = 0; fc < 8; ++fc) {
    int col = fc * 16 + (l & 15);
    float bv = bias[col];
#pragma unroll
    for (int fr = 0; fr < 2; ++fr) {
      int rbase = row0 + fr * 16 + g * 4;
#pragma unroll
      for (int reg = 0; reg < 4; ++reg) {
        int row = rbase + reg;
        if (row < n) {
          float v = acc[fr][fc][reg] + bv;
          if (relu) v = fmaxf(v, 0.f);
          out[(size_t)row * 128 + col] = pkb(v);
        }
      }
    }
  }
}

// ---------------- decoder: h1 = relu(Pv[lv]-Ph[lh]); stage2 MFMA; dot ----------

__global__ __launch_bounds__(256) void dec2_k(
    const unsigned short* __restrict__ Pv, const unsigned short* __restrict__ Ph,
    const int* __restrict__ lv, const int* __restrict__ lh,
    const unsigned short* __restrict__ W2b, const float* __restrict__ b2,
    const float* __restrict__ Wp, const float* __restrict__ bp,
    float* __restrict__ out, int L) {
  const int t = threadIdx.x;
  const int l = t & 63, wv = t >> 6;
  const int g = l >> 4;
  const int row0 = blockIdx.x * 64 + wv * 16;

  int rowc = row0 + (l & 15);
  rowc = rowc < L ? rowc : L - 1;
  const int iv = lv[rowc], ih = lh[rowc];
  const unsigned short* __restrict__ pv = Pv + (size_t)iv * 128 + g * 8;
  const unsigned short* __restrict__ ph = Ph + (size_t)ih * 128 + g * 8;

  uint4 A[4], B[4];
#pragma unroll
  for (int ch = 0; ch < 4; ++ch) A[ch] = *(const uint4*)(pv + ch * 32);
#pragma unroll
  for (int ch = 0; ch < 4; ++ch) B[ch] = *(const uint4*)(ph + ch * 32);

  s16x8 e[4];
#pragma unroll
  for (int ch = 0; ch < 4; ++ch) {
    U4S8 u;
    u.u.x = pk2(fmaxf(lo16(A[ch].x) - lo16(B[ch].x), 0.f), fmaxf(hi16(A[ch].x) - hi16(B[ch].x), 0.f));
    u.u.y = pk2(fmaxf(lo16(A[ch].y) - lo16(B[ch].y), 0.f), fmaxf(hi16(A[ch].y) - hi16(B[ch].y), 0.f));
    u.u.z = pk2(fmaxf(lo16(A[ch].z) - lo16(B[ch].z), 0.f), fmaxf(hi16(A[ch].z) - hi16(B[ch].z), 0.f));
    u.u.w = pk2(fmaxf(lo16(A[ch].w) - lo16(B[ch].w), 0.f), fmaxf(hi16(A[ch].w) - hi16(B[ch].w), 0.f));
    e[ch] = u.s;
  }

  f32x4 acc2[2] = {};
#pragma unroll
  for (int kc = 0; kc < 4; ++kc) {
#pragma unroll
    for (int fc = 0; fc < 2; ++fc) {
      s16x8 bv = *(const s16x8*)(W2b + (size_t)(fc * 16 + (l & 15)) * 128 + kc * 32 + g * 8);
      acc2[fc] = __builtin_amdgcn_mfma_f32_16x16x32_bf16(e[kc], bv, acc2[fc], 0, 0, 0);
    }
  }

  float p[4] = {0.f, 0.f, 0.f, 0.f};
#pragma unroll
  for (int fc = 0; fc < 2; ++fc) {
    int col = fc * 16 + (l & 15);
    float wp = Wp[col], bb = b2[col];
#pragma unroll
    for (int reg = 0; reg < 4; ++reg)
      p[reg] += fmaxf(acc2[fc][reg] + bb, 0.f) * wp;
  }
#pragma unroll
  for (int reg = 0; reg < 4; ++reg) {
    p[reg] += __shfl_xor(p[reg], 1);
    p[reg] += __shfl_xor(p[reg], 2);
    p[reg] += __shfl_xor(p[reg], 4);
    p[reg] += __shfl_xor(p[reg], 8);
  }
  if ((l & 15) == 0) {
    float bb = bp[0];
#pragma unroll
    for (int reg = 0; reg < 4; ++reg) {
      int row = row0 + g * 4 + reg;
      if (row < L) out[row] = p[reg] + bb;
    }
  }
}

// ---------------- host launcher ----------------

extern "C" void kernel_launch(void* const* d_in, const int* in_sizes, int n_in,
                              void* d_out, int out_size, void* d_ws, size_t ws_size,
                              hipStream_t stream) {
  const float* x_virus = (const float*)d_in[0];
  const float* x_host  = (const float*)d_in[1];
  const int* src_vh = (const int*)d_in[2];
  const int* dst_vh = (const int*)d_in[3];
  const int* src_hv = (const int*)d_in[4];
  const int* dst_hv = (const int*)d_in[5];
  const int* lbl_v  = (const int*)d_in[6];
  const int* lbl_h  = (const int*)d_in[7];
  const float* Wrel[4] = {(const float*)d_in[8],  (const float*)d_in[11],
                          (const float*)d_in[14], (const float*)d_in[17]};
  const float* Wroot[4] = {(const float*)d_in[10], (const float*)d_in[13],
                           (const float*)d_in[16], (const float*)d_in[19]};
  const float* bias_c[4] = {(const float*)d_in[9], (const float*)d_in[12],
                            (const float*)d_in[15], (const float*)d_in[18]};
  const float* W1 = (const float*)d_in[20];
  const float* b1 = (const float*)d_in[21];
  const float* W2 = (const float*)d_in[22];
  const float* b2 = (const float*)d_in[23];
  const float* Wp = (const float*)d_in[24];
  const float* bp = (const float*)d_in[25];

  const int NV = in_sizes[0] / D;
  const int NH = in_sizes[1] / D;
  const int E  = in_sizes[2];
  const int L  = in_sizes[6];

  // ---- workspace carve-up ----
  char* ws = (char*)d_ws;
  size_t o = 0;
  auto balloc = [&](size_t nb) { char* p = ws + o; o += (nb + 255) & ~(size_t)255; return p; };
  unsigned short* xvb   = (unsigned short*)balloc((size_t)NV * D * 2);
  unsigned short* xhb   = (unsigned short*)balloc((size_t)NH * D * 2);
  unsigned short* xv1b  = (unsigned short*)balloc((size_t)NV * D * 2);
  unsigned short* Pvb   = (unsigned short*)balloc((size_t)NV * D * 2);
  unsigned short* xh1b  = (unsigned short*)balloc((size_t)NH * D * 2);
  unsigned short* Phb   = (unsigned short*)balloc((size_t)NH * D * 2);
  unsigned short* mean_v = (unsigned short*)balloc((size_t)NV * D * 2);
  unsigned short* mean_h = (unsigned short*)balloc((size_t)NH * D * 2);
  unsigned short* Wcat0 = (unsigned short*)balloc(128 * 256 * 2);
  unsigned short* Wcat1 = (unsigned short*)balloc(128 * 256 * 2);
  unsigned short* WcatFh = (unsigned short*)balloc(128 * 256 * 2);
  unsigned short* WcatFv = (unsigned short*)balloc(128 * 256 * 2);
  unsigned short* W2b = (unsigned short*)balloc(32 * 128 * 2);
  float* biasFh = (float*)balloc(128 * 4);
  float* biasFv = (float*)balloc(128 * 4);
  float* inv_h = (float*)balloc((size_t)NH * 4);
  float* inv_v = (float*)balloc((size_t)NV * 4);
  int* cnt_h = (int*)balloc((size_t)NH * 4);
  int* cnt_v = (int*)balloc((size_t)NV * 4);
  int* off_h = (int*)balloc((size_t)NH * 4);
  int* off_v = (int*)balloc((size_t)NV * 4);
  int* csr_h = (int*)balloc((size_t)E * 4);
  int* csr_v = (int*)balloc((size_t)E * 4);
  int* histmat = (int*)balloc((size_t)512 * PGB * 4);
  int* histoff = (int*)balloc((size_t)512 * PGB * 4);
  unsigned* binned = (unsigned*)balloc((size_t)2 * E * 4);
  int* sums = (int*)balloc(512 * 4);

  auto cdiv = [](int a, int b) { return (a + b - 1) / b; };
  auto calc_shift = [](int n) { int s = 0; while ((1 << s) * 256 < n) ++s; return s; };

  const int shift0 = calc_shift(NH), shift1 = calc_shift(NV);
  const int nbins0 = cdiv(NH, 1 << shift0), nbins1 = cdiv(NV, 1 << shift1);
  const int nbinsTot = nbins0 + nbins1;
  const int nsc = nbinsTot * PGB;
  const int n4v = NV * D / 4, n4h = NH * D / 4;
  const int ncvt = cdiv(n4v + n4h, 256);

  // ---- fused histograms + conversions + weight prep ----
  hist_cvt_prep_k<<<512 + ncvt + 513, 256, 0, stream>>>(
      dst_vh, dst_hv, histmat, E, nbins0, nbins1, shift0, shift1,
      x_virus, xvb, n4v, x_host, xhb, n4h, ncvt,
      Wrel[0], Wroot[0], Wcat0,
      Wrel[1], Wroot[1], Wcat1,
      W1,
      Wrel[2], Wroot[2], bias_c[2], WcatFh, biasFh,
      Wrel[3], Wroot[3], bias_c[3], b1, WcatFv, biasFv,
      W2, W2b);

  // ---- scans + scatter + CSR finalize ----
  const int nchunks = cdiv(nsc, 1024);
  scan_chunk_k<<<nchunks, 256, 0, stream>>>(histmat, histoff, sums, nsc);
  scan_add2_k<<<cdiv(nsc, 256), 256, 0, stream>>>(histoff, sums, nsc, nchunks);
  part_scatter2_k<<<512, 256, 0, stream>>>(src_vh, dst_vh, src_hv, dst_hv,
                                           histoff, binned, E, nbins0, nbins1,
                                           shift0, shift1);
  csr_bin2_k<<<nbinsTot, 256, 0, stream>>>(binned, histoff,
                                           csr_h, off_h, cnt_h, inv_h,
                                           csr_v, off_v, cnt_v, inv_v,
                                           E, nbins0, nbinsTot, shift0, shift1, NH, NV);

  const int nbh4 = cdiv(NH, 4), nbv4 = cdiv(NV, 4);
  const int nbh128 = cdiv(NH, 128), nbv128 = cdiv(NV, 128);

  // ---- layer 0 (relu): merged agg then merged conv ----
  agg2_k<<<nbh4 + nbv4, 256, 0, stream>>>(
      xvb, csr_h, off_h, cnt_h, inv_h, mean_h, NH,
      xhb, csr_v, off_v, cnt_v, inv_v, mean_v, NV, nbh4);
  conv2_k<<<nbh128 + nbv128, 256, 0, stream>>>(
      mean_h, xhb, Wcat0, bias_c[0], xh1b, NH,
      mean_v, xvb, Wcat1, bias_c[1], xv1b, NV, nbh128, 1);

  // ---- layer 1 fused with W1 (no relu): produces Ph/Pv pre-activations ----
  agg2_k<<<nbh4 + nbv4, 256, 0, stream>>>(
      xv1b, csr_h, off_h, cnt_h, inv_h, mean_h, NH,
      xh1b, csr_v, off_v, cnt_v, inv_v, mean_v, NV, nbh4);
  conv2_k<<<nbh128 + nbv128, 256, 0, stream>>>(
      mean_h, xh1b, WcatFh, biasFh, Phb, NH,
      mean_v, xv1b, WcatFv, biasFv, Pvb, NV, nbh128, 0);

  // ---- decoder ----
  dec2_k<<<cdiv(L, 64), 256, 0, stream>>>(Pvb, Phb, lbl_v, lbl_h, W2b, b2,
                                          Wp, bp, (float*)d_out, L);
}